// Round 5
// baseline (1590.402 us; speedup 1.0000x reference)
//
#include <hip/hip_runtime.h>
#include <math.h>

#define Bb 16
#define Tt 32
#define Vv 26
#define Nn 500
#define Uu 64
#define Hh 512
#define CIN 209
#define K1P 224
#define Mm 512
#define Rr 256000
#define NB1 4000
#define NB23 2000

typedef short short8 __attribute__((ext_vector_type(8)));
typedef float f32x4 __attribute__((ext_vector_type(4)));

__device__ __forceinline__ float sigf(float x){ return 1.0f/(1.0f+expf(-x)); }
__device__ __forceinline__ float frcp(float x){ return __builtin_amdgcn_rcpf(x); }
__device__ __forceinline__ unsigned short f2bf(float f){
  unsigned u = __float_as_uint(f);
  unsigned r = u + 0x7fffu + ((u>>16)&1u);
  return (unsigned short)(r>>16);
}
__device__ __forceinline__ float bf2f(unsigned short h){
  return __uint_as_float(((unsigned)h)<<16);
}

__device__ __forceinline__ void mac44(float (&acc)[4][4], float a0,float a1,float a2,float a3, float4 bv){
  acc[0][0]=fmaf(a0,bv.x,acc[0][0]); acc[0][1]=fmaf(a0,bv.y,acc[0][1]); acc[0][2]=fmaf(a0,bv.z,acc[0][2]); acc[0][3]=fmaf(a0,bv.w,acc[0][3]);
  acc[1][0]=fmaf(a1,bv.x,acc[1][0]); acc[1][1]=fmaf(a1,bv.y,acc[1][1]); acc[1][2]=fmaf(a1,bv.z,acc[1][2]); acc[1][3]=fmaf(a1,bv.w,acc[1][3]);
  acc[2][0]=fmaf(a2,bv.x,acc[2][0]); acc[2][1]=fmaf(a2,bv.y,acc[2][1]); acc[2][2]=fmaf(a2,bv.z,acc[2][2]); acc[2][3]=fmaf(a2,bv.w,acc[2][3]);
  acc[3][0]=fmaf(a3,bv.x,acc[3][0]); acc[3][1]=fmaf(a3,bv.y,acc[3][1]); acc[3][2]=fmaf(a3,bv.w? a3:a3,acc[3][1]); // placeholder removed below
}

// NOTE: mac44 above intentionally unused remnant removed — real one follows.
__device__ __forceinline__ void mac44r(float (&acc)[4][4], float a0,float a1,float a2,float a3, float4 bv){
  acc[0][0]=fmaf(a0,bv.x,acc[0][0]); acc[0][1]=fmaf(a0,bv.y,acc[0][1]); acc[0][2]=fmaf(a0,bv.z,acc[0][2]); acc[0][3]=fmaf(a0,bv.w,acc[0][3]);
  acc[1][0]=fmaf(a1,bv.x,acc[1][0]); acc[1][1]=fmaf(a1,bv.y,acc[1][1]); acc[1][2]=fmaf(a1,bv.z,acc[1][2]); acc[1][3]=fmaf(a1,bv.w,acc[1][3]);
  acc[2][0]=fmaf(a2,bv.x,acc[2][0]); acc[2][1]=fmaf(a2,bv.y,acc[2][1]); acc[2][2]=fmaf(a2,bv.z,acc[2][2]); acc[2][3]=fmaf(a2,bv.w,acc[2][3]);
  acc[3][0]=fmaf(a3,bv.x,acc[3][0]); acc[3][1]=fmaf(a3,bv.y,acc[3][1]); acc[3][2]=fmaf(a3,bv.z,acc[3][2]); acc[3][3]=fmaf(a3,bv.w,acc[3][3]);
}

// device-scope grid barrier (counter monotone; blocks co-resident: 128 <= 256 CUs)
__device__ __forceinline__ void gridbar(unsigned* bar, unsigned expected){
  __syncthreads();
  __threadfence();
  if (threadIdx.x==0){
    __hip_atomic_fetch_add(bar, 1u, __ATOMIC_RELEASE, __HIP_MEMORY_SCOPE_AGENT);
    while (__hip_atomic_load(bar, __ATOMIC_ACQUIRE, __HIP_MEMORY_SCOPE_AGENT) < expected)
      __builtin_amdgcn_s_sleep(2);
  }
  __syncthreads();
  __threadfence();
}

// ---------------- combined weight prep: bf16 converts + transposes ----------------
__global__ void k_prep(const float* __restrict__ W2, const float* __restrict__ W3,
                       const float* __restrict__ WIH, const float* __restrict__ FC1W,
                       const float* __restrict__ FC2W,
                       unsigned short* __restrict__ W2B, unsigned short* __restrict__ W3B,
                       float* __restrict__ WIHT, float* __restrict__ FC1T,
                       float* __restrict__ FC2T){
  int idx = blockIdx.x*256 + threadIdx.x;
  if (idx < 8192){ W2B[idx] = f2bf(W2[idx]); return; }
  idx -= 8192;
  if (idx < 32768){ W3B[idx] = f2bf(W3[idx]); return; }
  idx -= 32768;
  if (idx < 1048576){ int r = idx>>9, c = idx&511; WIHT[c*2048+r] = WIH[idx]; return; }
  idx -= 1048576;
  if (idx < 32768){ int r = idx>>8, c = idx&255; FC1T[c*128+r] = FC1W[idx]; return; }
  idx -= 32768;
  if (idx < 8192){ int r = idx>>7, c = idx&127; FC2T[c*64+r] = FC2W[idx]; }
}

// ---------------- bn0 partial stats over the (recomputed-later) feature matrix ----------------
__global__ void k_feat_stats(const float* __restrict__ L, const float* __restrict__ PL,
                             const float* __restrict__ PI, const float* __restrict__ DSF,
                             float* __restrict__ ps0){
  int m = blockIdx.x;            // (b,t) pair, 0..511
  int b = m >> 5;
  int tid = threadIdx.x;
  __shared__ float pl_s[Nn], pi_s[Nn];
  for (int n=tid; n<Nn; n+=blockDim.x){ pl_s[n]=PL[b*Nn+n]; pi_s[n]=PI[b*Nn+n]; }
  __syncthreads();
  if (tid >= CIN) return;
  float sum=0.f, sq=0.f;
  if (tid < CIN-1){
    float li = L[m*208 + tid];
    if (li > 1e-5f){
      float cfac = sigf(DSF[0])*200000.0f;   // 1e6 * sig / 5
      float inv = frcp(li + 1e-6f);
      for (int n=0;n<Nn;n++){
        float pl = pl_s[n];
        float f = (pl > 1e-5f) ? __expf(-fabsf((pl-li)*inv)*cfac) : 0.f;
        sum += f; sq += f*f;
      }
    }
  } else {
    for (int n=0;n<Nn;n++){ float v=pi_s[n]; sum+=v; sq+=v*v; }
  }
  ps0[(size_t)m*CIN + tid] = sum;
  ps0[(size_t)(512+m)*CIN + tid] = sq;
}

// per-channel reduce of per-block partials -> (a, bb)
__global__ void k_reduce_ps(const float* __restrict__ ps, int NB, int C, float invCount,
                            const float* __restrict__ g, const float* __restrict__ bt,
                            float* __restrict__ abb){
  int c = blockIdx.x;
  int tid = threadIdx.x;
  float s=0.f, q=0.f;
  for (int nb=tid; nb<NB; nb+=256){
    s += ps[(size_t)nb*C + c];
    q += ps[(size_t)(NB+nb)*C + c];
  }
  #pragma unroll
  for (int off=1; off<64; off<<=1){ s += __shfl_xor(s,off); q += __shfl_xor(q,off); }
  __shared__ float rs[4], rq[4];
  if ((tid&63)==0){ rs[tid>>6]=s; rq[tid>>6]=q; }
  __syncthreads();
  if (tid==0){
    s = rs[0]+rs[1]+rs[2]+rs[3]; q = rq[0]+rq[1]+rq[2]+rq[3];
    float mean = s*invCount;
    float var  = q*invCount - mean*mean;
    float istd = rsqrtf(var + 1e-5f);
    float a = g[c]*istd;
    abb[c] = a;
    abb[C+c] = bt[c] - mean*a;
  }
}

// parallel per-column mean/var over Mrows -> (a, bb); one block per column
__global__ void k_colstats_par(const float* __restrict__ Z, int Mrows, int C,
                               const float* __restrict__ g, const float* __restrict__ bt,
                               float* __restrict__ abb){
  int c = blockIdx.x;
  int tid = threadIdx.x;
  float s=0.f,q=0.f;
  for (int r=tid; r<Mrows; r+=256){ float v=Z[(size_t)r*C+c]; s+=v; q+=v*v; }
  #pragma unroll
  for (int off=1; off<64; off<<=1){ s += __shfl_xor(s,off); q += __shfl_xor(q,off); }
  __shared__ float rs[4], rq[4];
  if ((tid&63)==0){ rs[tid>>6]=s; rq[tid>>6]=q; }
  __syncthreads();
  if (tid==0){
    s = rs[0]+rs[1]+rs[2]+rs[3]; q = rq[0]+rq[1]+rq[2]+rq[3];
    float mean = s/(float)Mrows;
    float var  = q/(float)Mrows - mean*mean;
    float istd = rsqrtf(var + 1e-5f);
    float a = g[c]*istd;
    abb[c]=a; abb[C+c]=bt[c]-mean*a;
  }
}

// fold bn0 into conv1 weights (parallel): one block per output channel o
__global__ void k_fold_w1p(const float* __restrict__ w1, const float* __restrict__ b1,
                           const float* __restrict__ abb0, unsigned short* __restrict__ w1b,
                           float* __restrict__ b1p){
  int o = blockIdx.x;
  int tid = threadIdx.x;
  float part = 0.f;
  for (int k=tid; k<K1P; k+=256){
    float w = (k < CIN) ? w1[o*CIN + k] : 0.f;
    float a = (k < CIN) ? abb0[k] : 0.f;
    w1b[o*K1P + k] = f2bf(w*a);
    if (k < CIN) part += w * abb0[CIN + k];
  }
  #pragma unroll
  for (int off=1; off<64; off<<=1) part += __shfl_xor(part,off);
  __shared__ float rs[4];
  if ((tid&63)==0) rs[tid>>6]=part;
  __syncthreads();
  if (tid==0) b1p[o] = b1[o] + rs[0]+rs[1]+rs[2]+rs[3];
}

// ---------------- conv1 MFMA: feature gen (fast exp recompute) -> bf16 LDS; Z1 f32 + bn1 partials ----
__launch_bounds__(256)
__global__ void k_conv1mf(const float* __restrict__ L, const float* __restrict__ PL,
                          const float* __restrict__ PI, const float* __restrict__ DSF,
                          const unsigned short* __restrict__ W1B, const float* __restrict__ b1p,
                          float* __restrict__ Z1, float* __restrict__ ps){
  __shared__ __align__(16) unsigned short Abuf[64*K1P];
  __shared__ __align__(16) unsigned short Bbuf[64*K1P];
  __shared__ float pl_s[64], pi_s[64];
  __shared__ float red[4][2][64];
  int tid = threadIdx.x;
  int r0 = blockIdx.x*64;
  if (tid < 64){
    int r = r0+tid; int m = r/500; int n = r - m*500; int b = m >> 5;
    pl_s[tid] = PL[b*Nn+n]; pi_s[tid] = PI[b*Nn+n];
  }
  for (int e=tid; e<64*28; e+=256){
    int row = e/28; int kc = (e - row*28)*8;
    short8 w = *(const short8*)&W1B[row*K1P + kc];
    unsigned byte = ((unsigned)(row*K1P + kc))*2u ^ (((unsigned)(row&7))<<4);
    *(short8*)((char*)Bbuf + byte) = w;
  }
  __syncthreads();
  float cfac = sigf(DSF[0])*200000.0f;
  for (int e=tid; e<64*28; e+=256){
    int row = e/28; int j0 = (e - row*28)*8;
    int am = (r0+row)/500;
    float pl = pl_s[row];
    float v[8];
    if (j0 < 208){
      float4 la = *(const float4*)&L[(size_t)am*208 + j0];
      float4 lb = *(const float4*)&L[(size_t)am*208 + j0 + 4];
      float li[8] = {la.x,la.y,la.z,la.w,lb.x,lb.y,lb.z,lb.w};
      #pragma unroll
      for (int j=0;j<8;j++)
        v[j] = (li[j] > 1e-5f && pl > 1e-5f)
             ? __expf(-fabsf((pl-li[j])*frcp(li[j]+1e-6f))*cfac) : 0.f;
    } else {
      #pragma unroll
      for (int j=0;j<8;j++) v[j] = 0.f;
      if (j0 == 208) v[0] = pi_s[row];
    }
    short8 st;
    #pragma unroll
    for (int j=0;j<8;j++) st[j] = (short)f2bf(v[j]);
    unsigned byte = ((unsigned)(row*K1P + j0))*2u ^ (((unsigned)(row&7))<<4);
    *(short8*)((char*)Abuf + byte) = st;
  }
  __syncthreads();
  int lane = tid&63, wid = tid>>6;
  int l15 = lane&15, lhi = lane>>4;
  int ar = wid*16 + l15;
  unsigned aswz = ((unsigned)(ar&7))<<4;
  f32x4 acc[4] = {};
  #pragma unroll
  for (int ks=0; ks<7; ks++){
    int kb = ks*32 + lhi*8;
    short8 af = *(const short8*)((const char*)Abuf + ((((unsigned)(ar*K1P + kb))*2u) ^ aswz));
    #pragma unroll
    for (int fj=0; fj<4; fj++){
      int bc = fj*16 + l15;
      short8 bfv = *(const short8*)((const char*)Bbuf + ((((unsigned)(bc*K1P + kb))*2u) ^ (((unsigned)(bc&7))<<4)));
      acc[fj] = __builtin_amdgcn_mfma_f32_16x16x32_bf16(af, bfv, acc[fj], 0, 0, 0);
    }
  }
  #pragma unroll
  for (int fj=0; fj<4; fj++){
    int ch = fj*16 + l15;
    float bc = b1p[ch];
    float s=0.f, q=0.f;
    #pragma unroll
    for (int qi=0; qi<4; qi++){
      float zv = acc[fj][qi] + bc;
      int rg = r0 + wid*16 + lhi*4 + qi;
      Z1[(size_t)rg*Uu + ch] = zv;
      s += zv; q += zv*zv;
    }
    s += __shfl_xor(s,16); s += __shfl_xor(s,32);
    q += __shfl_xor(q,16); q += __shfl_xor(q,32);
    if (lhi == 0){ red[wid][0][ch]=s; red[wid][1][ch]=q; }
  }
  __syncthreads();
  if (tid < 64){
    float s = red[0][0][tid]+red[1][0][tid]+red[2][0][tid]+red[3][0][tid];
    float q = red[0][1][tid]+red[1][1][tid]+red[2][1][tid]+red[3][1][tid];
    ps[(size_t)blockIdx.x*Uu + tid] = s;
    ps[(size_t)(NB1 + blockIdx.x)*Uu + tid] = q;
  }
}

// ---------------- MFMA conv: A = relu(bn(Xin)) as bf16, B = Wb (bf16 [c][k]) ----------------
template<int K, bool DOMAX, bool INBF>
__launch_bounds__(256)
__global__ void k_convmf(const void* __restrict__ Xin, const float* __restrict__ abbIn,
                         const unsigned short* __restrict__ Wb, int Ctot,
                         const float* __restrict__ bias, unsigned short* __restrict__ Zout,
                         float* __restrict__ ps, int NB,
                         float* __restrict__ pm, float* __restrict__ pn){
  __shared__ __align__(16) unsigned short Abuf[128*K];
  __shared__ __align__(16) unsigned short Bbuf[128*K];
  __shared__ float abbs[2*K];
  __shared__ float redS[2][128], redQ[2][128];
  __shared__ float mxS[2][DOMAX?2:1][128], mnS[2][DOMAX?2:1][128];
  int tid = threadIdx.x;
  int r0 = blockIdx.x*128;
  int c0 = blockIdx.y*128;
  for (int e=tid; e<2*K; e+=256) abbs[e] = abbIn[e];
  __syncthreads();
  constexpr int CPR = K/8;
  for (int e=tid; e<128*CPR; e+=256){
    int row = e/CPR; int kc = (e - row*CPR)*8;
    float v[8];
    if constexpr (INBF){
      short8 rawv = *(const short8*)((const unsigned short*)Xin + (size_t)(r0+row)*K + kc);
      #pragma unroll
      for (int j=0;j<8;j++) v[j] = bf2f((unsigned short)rawv[j]);
    } else {
      const float* zp = (const float*)Xin + (size_t)(r0+row)*K + kc;
      float4 za = *(const float4*)zp;
      float4 zb = *(const float4*)(zp+4);
      v[0]=za.x; v[1]=za.y; v[2]=za.z; v[3]=za.w; v[4]=zb.x; v[5]=zb.y; v[6]=zb.z; v[7]=zb.w;
    }
    short8 st;
    #pragma unroll
    for (int j=0;j<8;j++){
      float t = fmaxf(abbs[kc+j]*v[j] + abbs[K+kc+j], 0.f);
      st[j] = (short)f2bf(t);
    }
    unsigned byte = ((unsigned)(row*K + kc))*2u; byte ^= ((unsigned)(row&7))<<4;
    *(short8*)((char*)Abuf + byte) = st;
  }
  for (int e=tid; e<128*CPR; e+=256){
    int row = e/CPR; int kc = (e - row*CPR)*8;
    short8 w = *(const short8*)&Wb[(size_t)(c0+row)*K + kc];
    unsigned byte = ((unsigned)(row*K + kc))*2u; byte ^= ((unsigned)(row&7))<<4;
    *(short8*)((char*)Bbuf + byte) = w;
  }
  __syncthreads();

  int lane = tid&63, wid = tid>>6;
  int wr = wid>>1, wc = wid&1;
  int l15 = lane&15, lhi = lane>>4;
  f32x4 acc[4][4] = {};
  #pragma unroll
  for (int ks=0; ks<K/32; ks++){
    short8 af[4], bfr[4];
    int kb = ks*32 + lhi*8;
    #pragma unroll
    for (int f=0; f<4; f++){
      int arr = wr*64 + f*16 + l15;
      unsigned ab = ((unsigned)(arr*K + kb))*2u ^ (((unsigned)(arr&7))<<4);
      af[f] = *(const short8*)((const char*)Abuf + ab);
      int bc = wc*64 + f*16 + l15;
      unsigned bb = ((unsigned)(bc*K + kb))*2u ^ (((unsigned)(bc&7))<<4);
      bfr[f] = *(const short8*)((const char*)Bbuf + bb);
    }
    #pragma unroll
    for (int fi=0; fi<4; fi++)
      #pragma unroll
      for (int fj=0; fj<4; fj++)
        acc[fi][fj] = __builtin_amdgcn_mfma_f32_16x16x32_bf16(af[fi], bfr[fj], acc[fi][fj], 0, 0, 0);
  }

  int m0 = r0/500;
  int mhi = (m0+1)*500;
  #pragma unroll
  for (int fj=0; fj<4; fj++){
    int cg = c0 + wc*64 + fj*16 + l15;
    float bc = bias[cg];
    float s=0.f, q=0.f;
    float mx0=-INFINITY,mx1=-INFINITY,mn0=INFINITY,mn1=INFINITY;
    #pragma unroll
    for (int fi=0; fi<4; fi++){
      #pragma unroll
      for (int qi=0; qi<4; qi++){
        float zv = acc[fi][fj][qi] + bc;
        int rg = r0 + wr*64 + fi*16 + lhi*4 + qi;
        if (Zout) Zout[(size_t)rg*Ctot + cg] = f2bf(zv);
        s += zv; q += zv*zv;
        if constexpr (DOMAX){
          if (rg >= mhi){ mx1=fmaxf(mx1,zv); mn1=fminf(mn1,zv); }
          else          { mx0=fmaxf(mx0,zv); mn0=fminf(mn0,zv); }
        }
      }
    }
    s += __shfl_xor(s,16); s += __shfl_xor(s,32);
    q += __shfl_xor(q,16); q += __shfl_xor(q,32);
    if constexpr (DOMAX){
      mx0 = fmaxf(mx0, __shfl_xor(mx0,16)); mx0 = fmaxf(mx0, __shfl_xor(mx0,32));
      mx1 = fmaxf(mx1, __shfl_xor(mx1,16)); mx1 = fmaxf(mx1, __shfl_xor(mx1,32));
      mn0 = fminf(mn0, __shfl_xor(mn0,16)); mn0 = fminf(mn0, __shfl_xor(mn0,32));
      mn1 = fminf(mn1, __shfl_xor(mn1,16)); mn1 = fminf(mn1, __shfl_xor(mn1,32));
    }
    if (lhi == 0){
      int ch = wc*64 + fj*16 + l15;
      redS[wr][ch]=s; redQ[wr][ch]=q;
      if constexpr (DOMAX){
        mxS[wr][0][ch]=mx0; mxS[wr][1][ch]=mx1;
        mnS[wr][0][ch]=mn0; mnS[wr][1][ch]=mn1;
      }
    }
  }
  __syncthreads();
  if (tid < 128){
    float s = redS[0][tid]+redS[1][tid];
    float q = redQ[0][tid]+redQ[1][tid];
    size_t ci = (size_t)blockIdx.x*Ctot + c0 + tid;
    ps[ci] = s;
    ps[(size_t)NB*Ctot + ci] = q;
    if constexpr (DOMAX){
      #pragma unroll
      for (int g=0; g<2; g++){
        pm[((size_t)blockIdx.x*2+g)*Ctot + c0 + tid] = fmaxf(mxS[0][g][tid], mxS[1][g][tid]);
        pn[((size_t)blockIdx.x*2+g)*Ctot + c0 + tid] = fminf(mnS[0][g][tid], mnS[1][g][tid]);
      }
    }
  }
}

// per-(m,c) max/min over contributing row-blocks, fused with pool epilogue
__global__ void k_poolmm(const float* __restrict__ pm, const float* __restrict__ pn,
                         const float* __restrict__ abb3, float* __restrict__ P){
  int idx = blockIdx.x*blockDim.x + threadIdx.x;
  if (idx >= Mm*256) return;
  int m = idx>>8, c = idx&255;
  int bxlo = (500*m)/128;
  int bxhi = (500*m+499)/128;
  float mx=-INFINITY, mn=INFINITY;
  for (int bx=bxlo; bx<=bxhi; bx++){
    int m0 = (bx*128)/500;
    int gg = m - m0;
    if (gg==0 || gg==1){
      mx = fmaxf(mx, pm[((size_t)bx*2+gg)*256 + c]);
      mn = fminf(mn, pn[((size_t)bx*2+gg)*256 + c]);
    }
  }
  float a = abb3[c], bb = abb3[256+c];
  float zv = (a >= 0.f) ? mx : mn;
  P[idx] = fmaxf(a*zv + bb, 0.f);
}

// ---------------- generic tiled GEMM: C = opt_relu_bn(A) @ Wt + bias1 (+bias2) ----------------
__launch_bounds__(256)
__global__ void k_gemm(const float* __restrict__ A, const float* __restrict__ Wt,
                       const float* __restrict__ bias1, const float* __restrict__ bias2,
                       const float* __restrict__ abb,
                       float* __restrict__ Cmat, int Mrows, int Nc, int K){
  __shared__ float As[64][66];
  __shared__ float Bs[64][64];
  int tid = threadIdx.x;
  int r0 = blockIdx.x*64, c0 = blockIdx.y*64;
  int ty=tid>>4, tx=tid&15;
  float acc[4][4]={};
  for (int kc=0; kc<K; kc+=64){
    for (int e=tid; e<4096; e+=256){
      int i=e>>6, k=e&63;
      int r = r0+i;
      float v = (r < Mrows) ? A[(size_t)r*K + kc + k] : 0.f;
      if (abb) v = fmaxf(abb[kc+k]*v + abb[K+kc+k], 0.f);
      As[i][k]=v;
    }
    for (int e=tid; e<4096; e+=256){
      int k=e>>6, c=e&63;
      Bs[k][c] = Wt[(size_t)(kc+k)*Nc + c0 + c];
    }
    __syncthreads();
    #pragma unroll 4
    for (int k=0;k<64;k++){
      float a0=As[ty*4+0][k],a1=As[ty*4+1][k],a2=As[ty*4+2][k],a3=As[ty*4+3][k];
      float4 bv = *(const float4*)&Bs[k][tx*4];
      mac44r(acc,a0,a1,a2,a3,bv);
    }
    __syncthreads();
  }
  #pragma unroll
  for (int i=0;i<4;i++){
    int r = r0+ty*4+i; if (r >= Mrows) continue;
    #pragma unroll
    for (int j=0;j<4;j++){
      int c = c0+tx*4+j;
      float zv = acc[i][j] + bias1[c] + (bias2 ? bias2[c] : 0.f);
      Cmat[(size_t)r*Nc + c] = zv;
    }
  }
}

// ---------------- persistent LSTM: init + 32 steps + hT/cT output, grid barriers ----------------
__launch_bounds__(256)
__global__ void k_lstm_all(const float* __restrict__ h0, const float* __restrict__ c0,
                           const float* __restrict__ embw, const int* __restrict__ aa,
                           const float* __restrict__ whh, float* __restrict__ hb0,
                           float* __restrict__ hb1, float* __restrict__ lout,
                           float* __restrict__ out, unsigned* __restrict__ bar){
  __shared__ float h_s[16][516];
  __shared__ float g_s[16][16];
  int tid = threadIdx.x;
  int bid = blockIdx.x;
  int u0 = bid*4;
  float cv = 0.f;
  if (tid < 64){
    int idx = bid*64 + tid;
    hb0[idx] = h0[idx];
    cv = c0[(tid>>2)*512 + u0 + (tid&3)];
  }
  unsigned nbar = 0;
  gridbar(bar, ++nbar * 128u);
  int b = tid>>4, gu = tid&15, gate = gu>>2, uu = gu&3;
  int j = gate*512 + u0 + uu;
  const float4* wrow = (const float4*)&whh[(size_t)j*512];
  for (int t=0; t<32; t++){
    const float* hp = (t&1) ? hb1 : hb0;
    float* hn = (t&1) ? hb0 : hb1;
    for (int e=tid; e<16*512; e+=256) h_s[e>>9][e&511] = hp[e];
    __syncthreads();
    const float4* hrow = (const float4*)&h_s[b][0];
    float acc = 0.f;
    #pragma unroll 4
    for (int k=0;k<128;k++){
      float4 wv = wrow[k]; float4 hv = hrow[k];
      acc = fmaf(hv.x,wv.x,acc); acc = fmaf(hv.y,wv.y,acc);
      acc = fmaf(hv.z,wv.z,acc); acc = fmaf(hv.w,wv.w,acc);
    }
    int v = aa[b*Tt + t];
    acc += embw[(size_t)v*2048 + j];
    g_s[b][gu] = acc;
    __syncthreads();
    if (tid < 64){
      int bb2 = tid>>2, up = tid&3;
      float iv = g_s[bb2][0+up], fv = g_s[bb2][4+up], gv = g_s[bb2][8+up], ov = g_s[bb2][12+up];
      int ci = bb2*512 + u0 + up;
      float cn = sigf(fv)*cv + sigf(iv)*tanhf(gv);
      float hnv = sigf(ov)*tanhf(cn);
      cv = cn;
      hn[ci] = hnv;
      lout[(size_t)(bb2*Tt + t)*Hh + u0 + up] = hnv;
      if (t == 31){
        out[Mm*Vv + ci] = hnv;
        out[Mm*Vv + Bb*Hh + ci] = cn;
      }
    }
    if (t < 31) gridbar(bar, ++nbar * 128u);
  }
}

__global__ void k_logits(const float* __restrict__ Z5, const float* __restrict__ abb5,
                         const float* __restrict__ lout, const float* __restrict__ outw,
                         const float* __restrict__ outb, float* __restrict__ out){
  int idx = blockIdx.x*blockDim.x + threadIdx.x;
  if (idx >= Mm*Vv) return;
  int r = idx / Vv, o = idx - r*Vv;
  float acc = outb[o];
  for (int k=0;k<64;k++){
    float v = fmaxf(abb5[k]*Z5[(size_t)r*64+k] + abb5[64+k], 0.f);
    acc = fmaf(v, outw[o*576 + k], acc);
  }
  for (int k=0;k<512;k++){
    float v = fmaxf(lout[(size_t)r*512 + k], 0.f);
    acc = fmaf(v, outw[o*576 + 64 + k], acc);
  }
  out[idx] = acc;
}

extern "C" void kernel_launch(void* const* d_in, const int* in_sizes, int n_in,
                              void* d_out, int out_size, void* d_ws, size_t ws_size,
                              hipStream_t stream){
  (void)in_sizes; (void)n_in; (void)out_size; (void)ws_size;
  const float* L   = (const float*)d_in[0];
  const float* PL  = (const float*)d_in[1];
  const float* PI  = (const float*)d_in[2];
  const int*   AA  = (const int*)d_in[3];
  const float* H0  = (const float*)d_in[4];
  const float* C0  = (const float*)d_in[5];
  const float* DSF = (const float*)d_in[6];
  const float* W1  = (const float*)d_in[7];
  const float* B1  = (const float*)d_in[8];
  const float* W2  = (const float*)d_in[9];
  const float* B2  = (const float*)d_in[10];
  const float* W3  = (const float*)d_in[11];
  const float* B3  = (const float*)d_in[12];
  const float* FC1W= (const float*)d_in[13];
  const float* FC1B= (const float*)d_in[14];
  const float* FC2W= (const float*)d_in[15];
  const float* FC2B= (const float*)d_in[16];
  const float* G0=(const float*)d_in[17]; const float* Bt0=(const float*)d_in[18];
  const float* G1=(const float*)d_in[19]; const float* Bt1=(const float*)d_in[20];
  const float* G2=(const float*)d_in[21]; const float* Bt2=(const float*)d_in[22];
  const float* G3=(const float*)d_in[23]; const float* Bt3=(const float*)d_in[24];
  const float* G4=(const float*)d_in[25]; const float* Bt4=(const float*)d_in[26];
  const float* G5=(const float*)d_in[27]; const float* Bt5=(const float*)d_in[28];
  const float* EMB=(const float*)d_in[29];
  const float* WIH=(const float*)d_in[30];
  const float* WHH=(const float*)d_in[31];
  const float* BIH=(const float*)d_in[32];
  const float* BHH=(const float*)d_in[33];
  const float* OUTW=(const float*)d_in[34];
  const float* OUTB=(const float*)d_in[35];
  float* out = (float*)d_out;
  float* ws  = (float*)d_ws;

  size_t o = 0;
  float* Z1    = ws+o; o += (size_t)Rr*64;                 // f32
  unsigned short* Z2B = (unsigned short*)(ws+o); o += (size_t)Rr*64;  // Rr*128 bf16
  float* PS0   = ws+o; o += 2*512*CIN + 16;
  float* PS1   = ws+o; o += 2*NB1*64 + 16;
  float* PS2   = ws+o; o += 2*NB23*128 + 16;
  float* PS3   = ws+o; o += 2*NB23*256 + 16;
  float* PM3   = ws+o; o += NB23*2*256 + 16;
  float* PN3   = ws+o; o += NB23*2*256 + 16;
  float* ABB0  = ws+o; o += 432;
  float* ABB1  = ws+o; o += 128;
  float* ABB2  = ws+o; o += 256;
  float* ABB3  = ws+o; o += 512;
  float* ABB4  = ws+o; o += 256;
  float* ABB5  = ws+o; o += 128;
  unsigned short* W1B = (unsigned short*)(ws+o); o += 64*K1P/2 + 16;
  float* B1P   = ws+o; o += 64;
  unsigned short* W2B = (unsigned short*)(ws+o); o += 4096 + 16;
  unsigned short* W3B = (unsigned short*)(ws+o); o += 16384 + 16;
  float* Pm    = ws+o; o += 131072;
  float* Z4    = ws+o; o += 65536;
  float* Z5    = ws+o; o += 32768;
  float* EMBW  = ws+o; o += 53248;
  float* WIHT  = ws+o; o += 1048576;
  float* FC1T  = ws+o; o += 32768;
  float* FC2T  = ws+o; o += 8192;
  float* HB0   = ws+o; o += 8192;
  float* HB1   = ws+o; o += 8192;
  unsigned* BAR = (unsigned*)(ws+o); o += 64;
  float* LOUT  = ws+o; o += 262144;

  hipMemsetAsync(BAR, 0, 256, stream);

  // weight prep (independent of data) — single kernel
  k_prep<<<4416,256,0,stream>>>(W2,W3,WIH,FC1W,FC2W,W2B,W3B,WIHT,FC1T,FC2T);

  // point cloud branch
  k_feat_stats<<<512,256,0,stream>>>(L,PL,PI,DSF,PS0);
  k_reduce_ps<<<CIN,256,0,stream>>>(PS0, 512, CIN, 1.0f/(float)Rr, G0, Bt0, ABB0);
  k_fold_w1p<<<64,256,0,stream>>>(W1,B1,ABB0,W1B,B1P);
  k_conv1mf<<<NB1,256,0,stream>>>(L,PL,PI,DSF,W1B,B1P,Z1,PS1);
  k_reduce_ps<<<64,256,0,stream>>>(PS1, NB1, 64, 1.0f/(float)Rr, G1, Bt1, ABB1);
  k_convmf<64,false,false><<<dim3(NB23,1),256,0,stream>>>(Z1,ABB1,W2B,128,B2,Z2B,PS2,NB23,nullptr,nullptr);
  k_reduce_ps<<<128,256,0,stream>>>(PS2, NB23, 128, 1.0f/(float)Rr, G2, Bt2, ABB2);
  k_convmf<128,true,true><<<dim3(NB23,2),256,0,stream>>>(Z2B,ABB2,W3B,256,B3,nullptr,PS3,NB23,PM3,PN3);
  k_reduce_ps<<<256,256,0,stream>>>(PS3, NB23, 256, 1.0f/(float)Rr, G3, Bt3, ABB3);
  k_poolmm<<<512,256,0,stream>>>(PM3,PN3,ABB3,Pm);
  k_gemm<<<dim3(8,2),256,0,stream>>>(Pm,FC1T,FC1B,nullptr,nullptr,Z4,512,128,256);
  k_colstats_par<<<128,256,0,stream>>>(Z4,512,128,G4,Bt4,ABB4);
  k_gemm<<<dim3(8,1),256,0,stream>>>(Z4,FC2T,FC2B,nullptr,ABB4,Z5,512,64,128);
  k_colstats_par<<<64,256,0,stream>>>(Z5,512,64,G5,Bt5,ABB5);

  // LSTM branch — embw precompute then single persistent kernel
  k_gemm<<<dim3(1,32),256,0,stream>>>(EMB,WIHT,BIH,BHH,nullptr,EMBW,26,2048,512);
  k_lstm_all<<<128,256,0,stream>>>(H0,C0,EMBW,AA,WHH,HB0,HB1,LOUT,out,BAR);

  // output head
  k_logits<<<52,256,0,stream>>>(Z5,ABB5,LOUT,OUTW,OUTB,out);
}

// Round 6
// 969.264 us; speedup vs baseline: 1.6408x; 1.6408x over previous
//
#include <hip/hip_runtime.h>
#include <math.h>

#define Bb 16
#define Tt 32
#define Vv 26
#define Nn 500
#define Uu 64
#define Hh 512
#define CIN 209
#define K1P 224
#define Mm 512
#define Rr 256000
#define NB1 4000
#define NB23 2000

typedef short short8 __attribute__((ext_vector_type(8)));
typedef float f32x4 __attribute__((ext_vector_type(4)));

__device__ __forceinline__ float sigf(float x){ return 1.0f/(1.0f+expf(-x)); }
__device__ __forceinline__ float frcp(float x){ return __builtin_amdgcn_rcpf(x); }
__device__ __forceinline__ unsigned short f2bf(float f){
  unsigned u = __float_as_uint(f);
  unsigned r = u + 0x7fffu + ((u>>16)&1u);
  return (unsigned short)(r>>16);
}
__device__ __forceinline__ float bf2f(unsigned short h){
  return __uint_as_float(((unsigned)h)<<16);
}

__device__ __forceinline__ void mac44r(float (&acc)[4][4], float a0,float a1,float a2,float a3, float4 bv){
  acc[0][0]=fmaf(a0,bv.x,acc[0][0]); acc[0][1]=fmaf(a0,bv.y,acc[0][1]); acc[0][2]=fmaf(a0,bv.z,acc[0][2]); acc[0][3]=fmaf(a0,bv.w,acc[0][3]);
  acc[1][0]=fmaf(a1,bv.x,acc[1][0]); acc[1][1]=fmaf(a1,bv.y,acc[1][1]); acc[1][2]=fmaf(a1,bv.z,acc[1][2]); acc[1][3]=fmaf(a1,bv.w,acc[1][3]);
  acc[2][0]=fmaf(a2,bv.x,acc[2][0]); acc[2][1]=fmaf(a2,bv.y,acc[2][1]); acc[2][2]=fmaf(a2,bv.z,acc[2][2]); acc[2][3]=fmaf(a2,bv.w,acc[2][3]);
  acc[3][0]=fmaf(a3,bv.x,acc[3][0]); acc[3][1]=fmaf(a3,bv.y,acc[3][1]); acc[3][2]=fmaf(a3,bv.z,acc[3][2]); acc[3][3]=fmaf(a3,bv.w,acc[3][3]);
}

// ---------------- combined weight prep: bf16 converts + transposes ----------------
__global__ void k_prep(const float* __restrict__ W2, const float* __restrict__ W3,
                       const float* __restrict__ WIH, const float* __restrict__ FC1W,
                       const float* __restrict__ FC2W,
                       unsigned short* __restrict__ W2B, unsigned short* __restrict__ W3B,
                       float* __restrict__ WIHT, float* __restrict__ FC1T,
                       float* __restrict__ FC2T){
  int idx = blockIdx.x*256 + threadIdx.x;
  if (idx < 8192){ W2B[idx] = f2bf(W2[idx]); return; }
  idx -= 8192;
  if (idx < 32768){ W3B[idx] = f2bf(W3[idx]); return; }
  idx -= 32768;
  if (idx < 1048576){ int r = idx>>9, c = idx&511; WIHT[c*2048+r] = WIH[idx]; return; }
  idx -= 1048576;
  if (idx < 32768){ int r = idx>>8, c = idx&255; FC1T[c*128+r] = FC1W[idx]; return; }
  idx -= 32768;
  if (idx < 8192){ int r = idx>>7, c = idx&127; FC2T[c*64+r] = FC2W[idx]; }
}

// ---------------- bn0 partial stats over the (recomputed-later) feature matrix ----------------
__global__ void k_feat_stats(const float* __restrict__ L, const float* __restrict__ PL,
                             const float* __restrict__ PI, const float* __restrict__ DSF,
                             float* __restrict__ ps0){
  int m = blockIdx.x;            // (b,t) pair, 0..511
  int b = m >> 5;
  int tid = threadIdx.x;
  __shared__ float pl_s[Nn], pi_s[Nn];
  for (int n=tid; n<Nn; n+=blockDim.x){ pl_s[n]=PL[b*Nn+n]; pi_s[n]=PI[b*Nn+n]; }
  __syncthreads();
  if (tid >= CIN) return;
  float sum=0.f, sq=0.f;
  if (tid < CIN-1){
    float li = L[m*208 + tid];
    if (li > 1e-5f){
      float cfac = sigf(DSF[0])*200000.0f;   // 1e6 * sig / 5
      float inv = frcp(li + 1e-6f);
      for (int n=0;n<Nn;n++){
        float pl = pl_s[n];
        float f = (pl > 1e-5f) ? __expf(-fabsf((pl-li)*inv)*cfac) : 0.f;
        sum += f; sq += f*f;
      }
    }
  } else {
    for (int n=0;n<Nn;n++){ float v=pi_s[n]; sum+=v; sq+=v*v; }
  }
  ps0[(size_t)m*CIN + tid] = sum;
  ps0[(size_t)(512+m)*CIN + tid] = sq;
}

// per-channel reduce of per-block partials -> (a, bb)
__global__ void k_reduce_ps(const float* __restrict__ ps, int NB, int C, float invCount,
                            const float* __restrict__ g, const float* __restrict__ bt,
                            float* __restrict__ abb){
  int c = blockIdx.x;
  int tid = threadIdx.x;
  float s=0.f, q=0.f;
  for (int nb=tid; nb<NB; nb+=256){
    s += ps[(size_t)nb*C + c];
    q += ps[(size_t)(NB+nb)*C + c];
  }
  #pragma unroll
  for (int off=1; off<64; off<<=1){ s += __shfl_xor(s,off); q += __shfl_xor(q,off); }
  __shared__ float rs[4], rq[4];
  if ((tid&63)==0){ rs[tid>>6]=s; rq[tid>>6]=q; }
  __syncthreads();
  if (tid==0){
    s = rs[0]+rs[1]+rs[2]+rs[3]; q = rq[0]+rq[1]+rq[2]+rq[3];
    float mean = s*invCount;
    float var  = q*invCount - mean*mean;
    float istd = rsqrtf(var + 1e-5f);
    float a = g[c]*istd;
    abb[c] = a;
    abb[C+c] = bt[c] - mean*a;
  }
}

// parallel per-column mean/var over Mrows -> (a, bb); one block per column
__global__ void k_colstats_par(const float* __restrict__ Z, int Mrows, int C,
                               const float* __restrict__ g, const float* __restrict__ bt,
                               float* __restrict__ abb){
  int c = blockIdx.x;
  int tid = threadIdx.x;
  float s=0.f,q=0.f;
  for (int r=tid; r<Mrows; r+=256){ float v=Z[(size_t)r*C+c]; s+=v; q+=v*v; }
  #pragma unroll
  for (int off=1; off<64; off<<=1){ s += __shfl_xor(s,off); q += __shfl_xor(q,off); }
  __shared__ float rs[4], rq[4];
  if ((tid&63)==0){ rs[tid>>6]=s; rq[tid>>6]=q; }
  __syncthreads();
  if (tid==0){
    s = rs[0]+rs[1]+rs[2]+rs[3]; q = rq[0]+rq[1]+rq[2]+rq[3];
    float mean = s/(float)Mrows;
    float var  = q/(float)Mrows - mean*mean;
    float istd = rsqrtf(var + 1e-5f);
    float a = g[c]*istd;
    abb[c]=a; abb[C+c]=bt[c]-mean*a;
  }
}

// fold bn0 into conv1 weights (parallel): one block per output channel o
__global__ void k_fold_w1p(const float* __restrict__ w1, const float* __restrict__ b1,
                           const float* __restrict__ abb0, unsigned short* __restrict__ w1b,
                           float* __restrict__ b1p){
  int o = blockIdx.x;
  int tid = threadIdx.x;
  float part = 0.f;
  for (int k=tid; k<K1P; k+=256){
    float w = (k < CIN) ? w1[o*CIN + k] : 0.f;
    float a = (k < CIN) ? abb0[k] : 0.f;
    w1b[o*K1P + k] = f2bf(w*a);
    if (k < CIN) part += w * abb0[CIN + k];
  }
  #pragma unroll
  for (int off=1; off<64; off<<=1) part += __shfl_xor(part,off);
  __shared__ float rs[4];
  if ((tid&63)==0) rs[tid>>6]=part;
  __syncthreads();
  if (tid==0) b1p[o] = b1[o] + rs[0]+rs[1]+rs[2]+rs[3];
}

// ---------------- conv1 MFMA: feature gen (fast exp recompute) -> bf16 LDS; Z1 f32 + bn1 partials ----
__launch_bounds__(256)
__global__ void k_conv1mf(const float* __restrict__ L, const float* __restrict__ PL,
                          const float* __restrict__ PI, const float* __restrict__ DSF,
                          const unsigned short* __restrict__ W1B, const float* __restrict__ b1p,
                          float* __restrict__ Z1, float* __restrict__ ps){
  __shared__ __align__(16) unsigned short Abuf[64*K1P];
  __shared__ __align__(16) unsigned short Bbuf[64*K1P];
  __shared__ float pl_s[64], pi_s[64];
  __shared__ float red[4][2][64];
  int tid = threadIdx.x;
  int r0 = blockIdx.x*64;
  if (tid < 64){
    int r = r0+tid; int m = r/500; int n = r - m*500; int b = m >> 5;
    pl_s[tid] = PL[b*Nn+n]; pi_s[tid] = PI[b*Nn+n];
  }
  for (int e=tid; e<64*28; e+=256){
    int row = e/28; int kc = (e - row*28)*8;
    short8 w = *(const short8*)&W1B[row*K1P + kc];
    unsigned byte = ((unsigned)(row*K1P + kc))*2u ^ (((unsigned)(row&7))<<4);
    *(short8*)((char*)Bbuf + byte) = w;
  }
  __syncthreads();
  float cfac = sigf(DSF[0])*200000.0f;
  for (int e=tid; e<64*28; e+=256){
    int row = e/28; int j0 = (e - row*28)*8;
    int am = (r0+row)/500;
    float pl = pl_s[row];
    float v[8];
    if (j0 < 208){
      float4 la = *(const float4*)&L[(size_t)am*208 + j0];
      float4 lb = *(const float4*)&L[(size_t)am*208 + j0 + 4];
      float li[8] = {la.x,la.y,la.z,la.w,lb.x,lb.y,lb.z,lb.w};
      #pragma unroll
      for (int j=0;j<8;j++)
        v[j] = (li[j] > 1e-5f && pl > 1e-5f)
             ? __expf(-fabsf((pl-li[j])*frcp(li[j]+1e-6f))*cfac) : 0.f;
    } else {
      #pragma unroll
      for (int j=0;j<8;j++) v[j] = 0.f;
      if (j0 == 208) v[0] = pi_s[row];
    }
    short8 st;
    #pragma unroll
    for (int j=0;j<8;j++) st[j] = (short)f2bf(v[j]);
    unsigned byte = ((unsigned)(row*K1P + j0))*2u ^ (((unsigned)(row&7))<<4);
    *(short8*)((char*)Abuf + byte) = st;
  }
  __syncthreads();
  int lane = tid&63, wid = tid>>6;
  int l15 = lane&15, lhi = lane>>4;
  int ar = wid*16 + l15;
  unsigned aswz = ((unsigned)(ar&7))<<4;
  f32x4 acc[4] = {};
  #pragma unroll
  for (int ks=0; ks<7; ks++){
    int kb = ks*32 + lhi*8;
    short8 af = *(const short8*)((const char*)Abuf + ((((unsigned)(ar*K1P + kb))*2u) ^ aswz));
    #pragma unroll
    for (int fj=0; fj<4; fj++){
      int bc = fj*16 + l15;
      short8 bfv = *(const short8*)((const char*)Bbuf + ((((unsigned)(bc*K1P + kb))*2u) ^ (((unsigned)(bc&7))<<4)));
      acc[fj] = __builtin_amdgcn_mfma_f32_16x16x32_bf16(af, bfv, acc[fj], 0, 0, 0);
    }
  }
  #pragma unroll
  for (int fj=0; fj<4; fj++){
    int ch = fj*16 + l15;
    float bc = b1p[ch];
    float s=0.f, q=0.f;
    #pragma unroll
    for (int qi=0; qi<4; qi++){
      float zv = acc[fj][qi] + bc;
      int rg = r0 + wid*16 + lhi*4 + qi;
      Z1[(size_t)rg*Uu + ch] = zv;
      s += zv; q += zv*zv;
    }
    s += __shfl_xor(s,16); s += __shfl_xor(s,32);
    q += __shfl_xor(q,16); q += __shfl_xor(q,32);
    if (lhi == 0){ red[wid][0][ch]=s; red[wid][1][ch]=q; }
  }
  __syncthreads();
  if (tid < 64){
    float s = red[0][0][tid]+red[1][0][tid]+red[2][0][tid]+red[3][0][tid];
    float q = red[0][1][tid]+red[1][1][tid]+red[2][1][tid]+red[3][1][tid];
    ps[(size_t)blockIdx.x*Uu + tid] = s;
    ps[(size_t)(NB1 + blockIdx.x)*Uu + tid] = q;
  }
}

// ---------------- MFMA conv: A = relu(bn(Xin)) as bf16, B = Wb (bf16 [c][k]) ----------------
template<int K, bool DOMAX, bool INBF>
__launch_bounds__(256)
__global__ void k_convmf(const void* __restrict__ Xin, const float* __restrict__ abbIn,
                         const unsigned short* __restrict__ Wb, int Ctot,
                         const float* __restrict__ bias, unsigned short* __restrict__ Zout,
                         float* __restrict__ ps, int NB,
                         float* __restrict__ pm, float* __restrict__ pn){
  __shared__ __align__(16) unsigned short Abuf[128*K];
  __shared__ __align__(16) unsigned short Bbuf[128*K];
  __shared__ float abbs[2*K];
  __shared__ float redS[2][128], redQ[2][128];
  __shared__ float mxS[2][DOMAX?2:1][128], mnS[2][DOMAX?2:1][128];
  int tid = threadIdx.x;
  int r0 = blockIdx.x*128;
  int c0 = blockIdx.y*128;
  for (int e=tid; e<2*K; e+=256) abbs[e] = abbIn[e];
  __syncthreads();
  constexpr int CPR = K/8;
  for (int e=tid; e<128*CPR; e+=256){
    int row = e/CPR; int kc = (e - row*CPR)*8;
    float v[8];
    if constexpr (INBF){
      short8 rawv = *(const short8*)((const unsigned short*)Xin + (size_t)(r0+row)*K + kc);
      #pragma unroll
      for (int j=0;j<8;j++) v[j] = bf2f((unsigned short)rawv[j]);
    } else {
      const float* zp = (const float*)Xin + (size_t)(r0+row)*K + kc;
      float4 za = *(const float4*)zp;
      float4 zb = *(const float4*)(zp+4);
      v[0]=za.x; v[1]=za.y; v[2]=za.z; v[3]=za.w; v[4]=zb.x; v[5]=zb.y; v[6]=zb.z; v[7]=zb.w;
    }
    short8 st;
    #pragma unroll
    for (int j=0;j<8;j++){
      float t = fmaxf(abbs[kc+j]*v[j] + abbs[K+kc+j], 0.f);
      st[j] = (short)f2bf(t);
    }
    unsigned byte = ((unsigned)(row*K + kc))*2u; byte ^= ((unsigned)(row&7))<<4;
    *(short8*)((char*)Abuf + byte) = st;
  }
  for (int e=tid; e<128*CPR; e+=256){
    int row = e/CPR; int kc = (e - row*CPR)*8;
    short8 w = *(const short8*)&Wb[(size_t)(c0+row)*K + kc];
    unsigned byte = ((unsigned)(row*K + kc))*2u; byte ^= ((unsigned)(row&7))<<4;
    *(short8*)((char*)Bbuf + byte) = w;
  }
  __syncthreads();

  int lane = tid&63, wid = tid>>6;
  int wr = wid>>1, wc = wid&1;
  int l15 = lane&15, lhi = lane>>4;
  f32x4 acc[4][4] = {};
  #pragma unroll
  for (int ks=0; ks<K/32; ks++){
    short8 af[4], bfr[4];
    int kb = ks*32 + lhi*8;
    #pragma unroll
    for (int f=0; f<4; f++){
      int arr = wr*64 + f*16 + l15;
      unsigned ab = ((unsigned)(arr*K + kb))*2u ^ (((unsigned)(arr&7))<<4);
      af[f] = *(const short8*)((const char*)Abuf + ab);
      int bc = wc*64 + f*16 + l15;
      unsigned bb = ((unsigned)(bc*K + kb))*2u ^ (((unsigned)(bc&7))<<4);
      bfr[f] = *(const short8*)((const char*)Bbuf + bb);
    }
    #pragma unroll
    for (int fi=0; fi<4; fi++)
      #pragma unroll
      for (int fj=0; fj<4; fj++)
        acc[fi][fj] = __builtin_amdgcn_mfma_f32_16x16x32_bf16(af[fi], bfr[fj], acc[fi][fj], 0, 0, 0);
  }

  int m0 = r0/500;
  int mhi = (m0+1)*500;
  #pragma unroll
  for (int fj=0; fj<4; fj++){
    int cg = c0 + wc*64 + fj*16 + l15;
    float bc = bias[cg];
    float s=0.f, q=0.f;
    float mx0=-INFINITY,mx1=-INFINITY,mn0=INFINITY,mn1=INFINITY;
    #pragma unroll
    for (int fi=0; fi<4; fi++){
      #pragma unroll
      for (int qi=0; qi<4; qi++){
        float zv = acc[fi][fj][qi] + bc;
        int rg = r0 + wr*64 + fi*16 + lhi*4 + qi;
        if (Zout) Zout[(size_t)rg*Ctot + cg] = f2bf(zv);
        s += zv; q += zv*zv;
        if constexpr (DOMAX){
          if (rg >= mhi){ mx1=fmaxf(mx1,zv); mn1=fminf(mn1,zv); }
          else          { mx0=fmaxf(mx0,zv); mn0=fminf(mn0,zv); }
        }
      }
    }
    s += __shfl_xor(s,16); s += __shfl_xor(s,32);
    q += __shfl_xor(q,16); q += __shfl_xor(q,32);
    if constexpr (DOMAX){
      mx0 = fmaxf(mx0, __shfl_xor(mx0,16)); mx0 = fmaxf(mx0, __shfl_xor(mx0,32));
      mx1 = fmaxf(mx1, __shfl_xor(mx1,16)); mx1 = fmaxf(mx1, __shfl_xor(mx1,32));
      mn0 = fminf(mn0, __shfl_xor(mn0,16)); mn0 = fminf(mn0, __shfl_xor(mn0,32));
      mn1 = fminf(mn1, __shfl_xor(mn1,16)); mn1 = fminf(mn1, __shfl_xor(mn1,32));
    }
    if (lhi == 0){
      int ch = wc*64 + fj*16 + l15;
      redS[wr][ch]=s; redQ[wr][ch]=q;
      if constexpr (DOMAX){
        mxS[wr][0][ch]=mx0; mxS[wr][1][ch]=mx1;
        mnS[wr][0][ch]=mn0; mnS[wr][1][ch]=mn1;
      }
    }
  }
  __syncthreads();
  if (tid < 128){
    float s = redS[0][tid]+redS[1][tid];
    float q = redQ[0][tid]+redQ[1][tid];
    size_t ci = (size_t)blockIdx.x*Ctot + c0 + tid;
    ps[ci] = s;
    ps[(size_t)NB*Ctot + ci] = q;
    if constexpr (DOMAX){
      #pragma unroll
      for (int g=0; g<2; g++){
        pm[((size_t)blockIdx.x*2+g)*Ctot + c0 + tid] = fmaxf(mxS[0][g][tid], mxS[1][g][tid]);
        pn[((size_t)blockIdx.x*2+g)*Ctot + c0 + tid] = fminf(mnS[0][g][tid], mnS[1][g][tid]);
      }
    }
  }
}

// per-(m,c) max/min over contributing row-blocks, fused with pool epilogue
__global__ void k_poolmm(const float* __restrict__ pm, const float* __restrict__ pn,
                         const float* __restrict__ abb3, float* __restrict__ P){
  int idx = blockIdx.x*blockDim.x + threadIdx.x;
  if (idx >= Mm*256) return;
  int m = idx>>8, c = idx&255;
  int bxlo = (500*m)/128;
  int bxhi = (500*m+499)/128;
  float mx=-INFINITY, mn=INFINITY;
  for (int bx=bxlo; bx<=bxhi; bx++){
    int m0 = (bx*128)/500;
    int gg = m - m0;
    if (gg==0 || gg==1){
      mx = fmaxf(mx, pm[((size_t)bx*2+gg)*256 + c]);
      mn = fminf(mn, pn[((size_t)bx*2+gg)*256 + c]);
    }
  }
  float a = abb3[c], bb = abb3[256+c];
  float zv = (a >= 0.f) ? mx : mn;
  P[idx] = fmaxf(a*zv + bb, 0.f);
}

// ---------------- generic tiled GEMM: C = opt_relu_bn(A) @ Wt + bias1 (+bias2) ----------------
__launch_bounds__(256)
__global__ void k_gemm(const float* __restrict__ A, const float* __restrict__ Wt,
                       const float* __restrict__ bias1, const float* __restrict__ bias2,
                       const float* __restrict__ abb,
                       float* __restrict__ Cmat, int Mrows, int Nc, int K){
  __shared__ float As[64][66];
  __shared__ float Bs[64][64];
  int tid = threadIdx.x;
  int r0 = blockIdx.x*64, c0 = blockIdx.y*64;
  int ty=tid>>4, tx=tid&15;
  float acc[4][4]={};
  for (int kc=0; kc<K; kc+=64){
    for (int e=tid; e<4096; e+=256){
      int i=e>>6, k=e&63;
      int r = r0+i;
      float v = (r < Mrows) ? A[(size_t)r*K + kc + k] : 0.f;
      if (abb) v = fmaxf(abb[kc+k]*v + abb[K+kc+k], 0.f);
      As[i][k]=v;
    }
    for (int e=tid; e<4096; e+=256){
      int k=e>>6, c=e&63;
      Bs[k][c] = Wt[(size_t)(kc+k)*Nc + c0 + c];
    }
    __syncthreads();
    #pragma unroll 4
    for (int k=0;k<64;k++){
      float a0=As[ty*4+0][k],a1=As[ty*4+1][k],a2=As[ty*4+2][k],a3=As[ty*4+3][k];
      float4 bv = *(const float4*)&Bs[k][tx*4];
      mac44r(acc,a0,a1,a2,a3,bv);
    }
    __syncthreads();
  }
  #pragma unroll
  for (int i=0;i<4;i++){
    int r = r0+ty*4+i; if (r >= Mrows) continue;
    #pragma unroll
    for (int j=0;j<4;j++){
      int c = c0+tx*4+j;
      float zv = acc[i][j] + bias1[c] + (bias2 ? bias2[c] : 0.f);
      Cmat[(size_t)r*Nc + c] = zv;
    }
  }
}

__global__ void k_init_hc(const float* __restrict__ h0, const float* __restrict__ c0,
                          float* __restrict__ hb, float* __restrict__ cb){
  int i = blockIdx.x*blockDim.x + threadIdx.x;
  if (i < Bb*Hh){ hb[i]=h0[i]; cb[i]=c0[i]; }
}

// one step of the LSTM; 128 blocks x 256 thr; block handles 4 u-columns x 4 gates x 16 batch
__launch_bounds__(256)
__global__ void k_lstm_step(const float* __restrict__ hprev, float* __restrict__ hnext,
                            float* __restrict__ cbuf, const float* __restrict__ embw,
                            const int* __restrict__ aa, const float* __restrict__ whh,
                            float* __restrict__ lout, int t){
  __shared__ float h_s[16][516];
  __shared__ float g_s[16][16];
  int tid = threadIdx.x;
  int u0 = blockIdx.x*4;
  for (int e=tid; e<2048; e+=256){
    int idx = e*4;
    *(float4*)&h_s[idx>>9][idx&511] = *(const float4*)&hprev[idx];
  }
  __syncthreads();
  int b = tid>>4, gu = tid&15, gate = gu>>2, uu = gu&3;
  int j = gate*512 + u0 + uu;
  const float4* wrow = (const float4*)&whh[(size_t)j*512];
  const float4* hrow = (const float4*)&h_s[b][0];
  float acc = 0.f;
  #pragma unroll 4
  for (int k=0;k<128;k++){
    float4 wv = wrow[k]; float4 hv = hrow[k];
    acc = fmaf(hv.x,wv.x,acc); acc = fmaf(hv.y,wv.y,acc);
    acc = fmaf(hv.z,wv.z,acc); acc = fmaf(hv.w,wv.w,acc);
  }
  int v = aa[b*Tt + t];
  acc += embw[(size_t)v*2048 + j];
  g_s[b][gu] = acc;
  __syncthreads();
  if (tid < 64){
    int bb = tid>>2, up = tid&3;
    float iv = g_s[bb][0+up], fv = g_s[bb][4+up], gv = g_s[bb][8+up], ov = g_s[bb][12+up];
    int ci = bb*512 + u0 + up;
    float cn = sigf(fv)*cbuf[ci] + sigf(iv)*tanhf(gv);
    float hn = sigf(ov)*tanhf(cn);
    cbuf[ci]=cn; hnext[ci]=hn;
    lout[(size_t)(bb*Tt + t)*Hh + u0 + up] = hn;
  }
}

__global__ void k_out_hc(const float* __restrict__ hb, const float* __restrict__ cb,
                         float* __restrict__ out){
  int i = blockIdx.x*blockDim.x + threadIdx.x;
  if (i < Bb*Hh){ out[Mm*Vv + i] = hb[i]; out[Mm*Vv + Bb*Hh + i] = cb[i]; }
}

__global__ void k_logits(const float* __restrict__ Z5, const float* __restrict__ abb5,
                         const float* __restrict__ lout, const float* __restrict__ outw,
                         const float* __restrict__ outb, float* __restrict__ out){
  int idx = blockIdx.x*blockDim.x + threadIdx.x;
  if (idx >= Mm*Vv) return;
  int r = idx / Vv, o = idx - r*Vv;
  float acc = outb[o];
  for (int k=0;k<64;k++){
    float v = fmaxf(abb5[k]*Z5[(size_t)r*64+k] + abb5[64+k], 0.f);
    acc = fmaf(v, outw[o*576 + k], acc);
  }
  for (int k=0;k<512;k++){
    float v = fmaxf(lout[(size_t)r*512 + k], 0.f);
    acc = fmaf(v, outw[o*576 + 64 + k], acc);
  }
  out[idx] = acc;
}

extern "C" void kernel_launch(void* const* d_in, const int* in_sizes, int n_in,
                              void* d_out, int out_size, void* d_ws, size_t ws_size,
                              hipStream_t stream){
  (void)in_sizes; (void)n_in; (void)out_size; (void)ws_size;
  const float* L   = (const float*)d_in[0];
  const float* PL  = (const float*)d_in[1];
  const float* PI  = (const float*)d_in[2];
  const int*   AA  = (const int*)d_in[3];
  const float* H0  = (const float*)d_in[4];
  const float* C0  = (const float*)d_in[5];
  const float* DSF = (const float*)d_in[6];
  const float* W1  = (const float*)d_in[7];
  const float* B1  = (const float*)d_in[8];
  const float* W2  = (const float*)d_in[9];
  const float* B2  = (const float*)d_in[10];
  const float* W3  = (const float*)d_in[11];
  const float* B3  = (const float*)d_in[12];
  const float* FC1W= (const float*)d_in[13];
  const float* FC1B= (const float*)d_in[14];
  const float* FC2W= (const float*)d_in[15];
  const float* FC2B= (const float*)d_in[16];
  const float* G0=(const float*)d_in[17]; const float* Bt0=(const float*)d_in[18];
  const float* G1=(const float*)d_in[19]; const float* Bt1=(const float*)d_in[20];
  const float* G2=(const float*)d_in[21]; const float* Bt2=(const float*)d_in[22];
  const float* G3=(const float*)d_in[23]; const float* Bt3=(const float*)d_in[24];
  const float* G4=(const float*)d_in[25]; const float* Bt4=(const float*)d_in[26];
  const float* G5=(const float*)d_in[27]; const float* Bt5=(const float*)d_in[28];
  const float* EMB=(const float*)d_in[29];
  const float* WIH=(const float*)d_in[30];
  const float* WHH=(const float*)d_in[31];
  const float* BIH=(const float*)d_in[32];
  const float* BHH=(const float*)d_in[33];
  const float* OUTW=(const float*)d_in[34];
  const float* OUTB=(const float*)d_in[35];
  float* out = (float*)d_out;
  float* ws  = (float*)d_ws;

  size_t o = 0;
  float* Z1    = ws+o; o += (size_t)Rr*64;                 // f32
  unsigned short* Z2B = (unsigned short*)(ws+o); o += (size_t)Rr*64;  // Rr*128 bf16
  float* PS0   = ws+o; o += 2*512*CIN + 16;
  float* PS1   = ws+o; o += 2*NB1*64 + 16;
  float* PS2   = ws+o; o += 2*NB23*128 + 16;
  float* PS3   = ws+o; o += 2*NB23*256 + 16;
  float* PM3   = ws+o; o += NB23*2*256 + 16;
  float* PN3   = ws+o; o += NB23*2*256 + 16;
  float* ABB0  = ws+o; o += 432;
  float* ABB1  = ws+o; o += 128;
  float* ABB2  = ws+o; o += 256;
  float* ABB3  = ws+o; o += 512;
  float* ABB4  = ws+o; o += 256;
  float* ABB5  = ws+o; o += 128;
  unsigned short* W1B = (unsigned short*)(ws+o); o += 64*K1P/2 + 16;
  float* B1P   = ws+o; o += 64;
  unsigned short* W2B = (unsigned short*)(ws+o); o += 4096 + 16;
  unsigned short* W3B = (unsigned short*)(ws+o); o += 16384 + 16;
  float* Pm    = ws+o; o += 131072;
  float* Z4    = ws+o; o += 65536;
  float* Z5    = ws+o; o += 32768;
  float* EMBW  = ws+o; o += 53248;
  float* WIHT  = ws+o; o += 1048576;
  float* FC1T  = ws+o; o += 32768;
  float* FC2T  = ws+o; o += 8192;
  float* HB0   = ws+o; o += 8192;
  float* HB1   = ws+o; o += 8192;
  float* CB    = ws+o; o += 8192;
  float* LOUT  = ws+o; o += 262144;

  // weight prep (independent of data) — single kernel
  k_prep<<<4416,256,0,stream>>>(W2,W3,WIH,FC1W,FC2W,W2B,W3B,WIHT,FC1T,FC2T);

  // point cloud branch
  k_feat_stats<<<512,256,0,stream>>>(L,PL,PI,DSF,PS0);
  k_reduce_ps<<<CIN,256,0,stream>>>(PS0, 512, CIN, 1.0f/(float)Rr, G0, Bt0, ABB0);
  k_fold_w1p<<<64,256,0,stream>>>(W1,B1,ABB0,W1B,B1P);
  k_conv1mf<<<NB1,256,0,stream>>>(L,PL,PI,DSF,W1B,B1P,Z1,PS1);
  k_reduce_ps<<<64,256,0,stream>>>(PS1, NB1, 64, 1.0f/(float)Rr, G1, Bt1, ABB1);
  k_convmf<64,false,false><<<dim3(NB23,1),256,0,stream>>>(Z1,ABB1,W2B,128,B2,Z2B,PS2,NB23,nullptr,nullptr);
  k_reduce_ps<<<128,256,0,stream>>>(PS2, NB23, 128, 1.0f/(float)Rr, G2, Bt2, ABB2);
  k_convmf<128,true,true><<<dim3(NB23,2),256,0,stream>>>(Z2B,ABB2,W3B,256,B3,nullptr,PS3,NB23,PM3,PN3);
  k_reduce_ps<<<256,256,0,stream>>>(PS3, NB23, 256, 1.0f/(float)Rr, G3, Bt3, ABB3);
  k_poolmm<<<512,256,0,stream>>>(PM3,PN3,ABB3,Pm);
  k_gemm<<<dim3(8,2),256,0,stream>>>(Pm,FC1T,FC1B,nullptr,nullptr,Z4,512,128,256);
  k_colstats_par<<<128,256,0,stream>>>(Z4,512,128,G4,Bt4,ABB4);
  k_gemm<<<dim3(8,1),256,0,stream>>>(Z4,FC2T,FC2B,nullptr,ABB4,Z5,512,64,128);
  k_colstats_par<<<64,256,0,stream>>>(Z5,512,64,G5,Bt5,ABB5);

  // LSTM branch — embw precompute then 32 step launches (graph-replayed; cheaper than grid sync)
  k_gemm<<<dim3(1,32),256,0,stream>>>(EMB,WIHT,BIH,BHH,nullptr,EMBW,26,2048,512);
  k_init_hc<<<32,256,0,stream>>>(H0,C0,HB0,CB);
  for (int t=0;t<32;t++){
    float* hp = (t&1)?HB1:HB0;
    float* hn = (t&1)?HB0:HB1;
    k_lstm_step<<<128,256,0,stream>>>(hp,hn,CB,EMBW,AA,WHH,LOUT,t);
  }
  k_out_hc<<<32,256,0,stream>>>(HB0,CB,out);

  // output head
  k_logits<<<52,256,0,stream>>>(Z5,ABB5,LOUT,OUTW,OUTB,out);
}

// Round 7
// 807.728 us; speedup vs baseline: 1.9690x; 1.2000x over previous
//
#include <hip/hip_runtime.h>
#include <hip/hip_bf16.h>
#include <math.h>

#define Bb 16
#define Tt 32
#define Vv 26
#define Nn 500
#define Uu 64
#define Hh 512
#define CIN 209
#define K1P 224
#define Mm 512
#define Rr 256000
#define NB1 4000
#define NB23 2000

typedef short short8 __attribute__((ext_vector_type(8)));
typedef float f32x4 __attribute__((ext_vector_type(4)));

__device__ __forceinline__ float sigf(float x){ return 1.0f/(1.0f+expf(-x)); }
__device__ __forceinline__ float frcp(float x){ return __builtin_amdgcn_rcpf(x); }
__device__ __forceinline__ unsigned short f2bf(float f){
  __hip_bfloat16 h = __float2bfloat16(f);
  return *reinterpret_cast<unsigned short*>(&h);
}
__device__ __forceinline__ float bf2f(unsigned short h){
  return __uint_as_float(((unsigned)h)<<16);
}

__device__ __forceinline__ void mac44r(float (&acc)[4][4], float a0,float a1,float a2,float a3, float4 bv){
  acc[0][0]=fmaf(a0,bv.x,acc[0][0]); acc[0][1]=fmaf(a0,bv.y,acc[0][1]); acc[0][2]=fmaf(a0,bv.z,acc[0][2]); acc[0][3]=fmaf(a0,bv.w,acc[0][3]);
  acc[1][0]=fmaf(a1,bv.x,acc[1][0]); acc[1][1]=fmaf(a1,bv.y,acc[1][1]); acc[1][2]=fmaf(a1,bv.z,acc[1][2]); acc[1][3]=fmaf(a1,bv.w,acc[1][3]);
  acc[2][0]=fmaf(a2,bv.x,acc[2][0]); acc[2][1]=fmaf(a2,bv.y,acc[2][1]); acc[2][2]=fmaf(a2,bv.z,acc[2][2]); acc[2][3]=fmaf(a2,bv.w,acc[2][3]);
  acc[3][0]=fmaf(a3,bv.x,acc[3][0]); acc[3][1]=fmaf(a3,bv.y,acc[3][1]); acc[3][2]=fmaf(a3,bv.z,acc[3][2]); acc[3][3]=fmaf(a3,bv.w,acc[3][3]);
}

// ---------------- LDS-tiled transpose (coalesced read AND write), 64x64 tiles ----------------
__global__ void k_transT(const float* __restrict__ src, float* __restrict__ dst, int rows, int cols){
  __shared__ float t[64][65];
  int r0 = blockIdx.y*64, c0 = blockIdx.x*64;
  int tid = threadIdx.x;
  int tr = tid>>6, tc = tid&63;
  #pragma unroll
  for (int i=0;i<16;i++){
    int r = tr + i*4;
    t[r][tc] = src[(size_t)(r0+r)*cols + c0+tc];
  }
  __syncthreads();
  #pragma unroll
  for (int i=0;i<16;i++){
    int r = tr + i*4;
    dst[(size_t)(c0+r)*rows + r0+tc] = t[tc][r];
  }
}

// ---------------- small weight prep: bf16 converts + small transposes ----------------
__global__ void k_prep(const float* __restrict__ W2, const float* __restrict__ W3,
                       const float* __restrict__ FC1W, const float* __restrict__ FC2W,
                       unsigned short* __restrict__ W2B, unsigned short* __restrict__ W3B,
                       float* __restrict__ FC1T, float* __restrict__ FC2T){
  int idx = blockIdx.x*256 + threadIdx.x;
  if (idx < 8192){ W2B[idx] = f2bf(W2[idx]); return; }
  idx -= 8192;
  if (idx < 32768){ W3B[idx] = f2bf(W3[idx]); return; }
  idx -= 32768;
  if (idx < 32768){ int r = idx>>8, c = idx&255; FC1T[c*128+r] = FC1W[idx]; return; }
  idx -= 32768;
  if (idx < 8192){ int r = idx>>7, c = idx&127; FC2T[c*64+r] = FC2W[idx]; }
}

// ---------------- bn0 partial stats over the (recomputed-later) feature matrix ----------------
__global__ void k_feat_stats(const float* __restrict__ L, const float* __restrict__ PL,
                             const float* __restrict__ PI, const float* __restrict__ DSF,
                             float* __restrict__ ps0){
  int m = blockIdx.x;            // (b,t) pair, 0..511
  int b = m >> 5;
  int tid = threadIdx.x;
  __shared__ float pl_s[Nn], pi_s[Nn];
  for (int n=tid; n<Nn; n+=blockDim.x){ pl_s[n]=PL[b*Nn+n]; pi_s[n]=PI[b*Nn+n]; }
  __syncthreads();
  if (tid >= CIN) return;
  float sum=0.f, sq=0.f;
  if (tid < CIN-1){
    float li = L[m*208 + tid];
    if (li > 1e-5f){
      float cfac = sigf(DSF[0])*200000.0f;   // 1e6 * sig / 5
      float inv = frcp(li + 1e-6f);
      for (int n=0;n<Nn;n++){
        float pl = pl_s[n];
        float f = (pl > 1e-5f) ? __expf(-fabsf((pl-li)*inv)*cfac) : 0.f;
        sum += f; sq += f*f;
      }
    }
  } else {
    for (int n=0;n<Nn;n++){ float v=pi_s[n]; sum+=v; sq+=v*v; }
  }
  ps0[(size_t)m*CIN + tid] = sum;
  ps0[(size_t)(512+m)*CIN + tid] = sq;
}

// per-channel reduce of per-block partials -> (a, bb)
__global__ void k_reduce_ps(const float* __restrict__ ps, int NB, int C, float invCount,
                            const float* __restrict__ g, const float* __restrict__ bt,
                            float* __restrict__ abb){
  int c = blockIdx.x;
  int tid = threadIdx.x;
  float s=0.f, q=0.f;
  for (int nb=tid; nb<NB; nb+=256){
    s += ps[(size_t)nb*C + c];
    q += ps[(size_t)(NB+nb)*C + c];
  }
  #pragma unroll
  for (int off=1; off<64; off<<=1){ s += __shfl_xor(s,off); q += __shfl_xor(q,off); }
  __shared__ float rs[4], rq[4];
  if ((tid&63)==0){ rs[tid>>6]=s; rq[tid>>6]=q; }
  __syncthreads();
  if (tid==0){
    s = rs[0]+rs[1]+rs[2]+rs[3]; q = rq[0]+rq[1]+rq[2]+rq[3];
    float mean = s*invCount;
    float var  = q*invCount - mean*mean;
    float istd = rsqrtf(var + 1e-5f);
    float a = g[c]*istd;
    abb[c] = a;
    abb[C+c] = bt[c] - mean*a;
  }
}

// parallel per-column mean/var over Mrows -> (a, bb); one block per column
__global__ void k_colstats_par(const float* __restrict__ Z, int Mrows, int C,
                               const float* __restrict__ g, const float* __restrict__ bt,
                               float* __restrict__ abb){
  int c = blockIdx.x;
  int tid = threadIdx.x;
  float s=0.f,q=0.f;
  for (int r=tid; r<Mrows; r+=256){ float v=Z[(size_t)r*C+c]; s+=v; q+=v*v; }
  #pragma unroll
  for (int off=1; off<64; off<<=1){ s += __shfl_xor(s,off); q += __shfl_xor(q,off); }
  __shared__ float rs[4], rq[4];
  if ((tid&63)==0){ rs[tid>>6]=s; rq[tid>>6]=q; }
  __syncthreads();
  if (tid==0){
    s = rs[0]+rs[1]+rs[2]+rs[3]; q = rq[0]+rq[1]+rq[2]+rq[3];
    float mean = s/(float)Mrows;
    float var  = q/(float)Mrows - mean*mean;
    float istd = rsqrtf(var + 1e-5f);
    float a = g[c]*istd;
    abb[c]=a; abb[C+c]=bt[c]-mean*a;
  }
}

// fold bn0 into conv1 weights (parallel): one block per output channel o
__global__ void k_fold_w1p(const float* __restrict__ w1, const float* __restrict__ b1,
                           const float* __restrict__ abb0, unsigned short* __restrict__ w1b,
                           float* __restrict__ b1p){
  int o = blockIdx.x;
  int tid = threadIdx.x;
  float part = 0.f;
  for (int k=tid; k<K1P; k+=256){
    float w = (k < CIN) ? w1[o*CIN + k] : 0.f;
    float a = (k < CIN) ? abb0[k] : 0.f;
    w1b[o*K1P + k] = f2bf(w*a);
    if (k < CIN) part += w * abb0[CIN + k];
  }
  #pragma unroll
  for (int off=1; off<64; off<<=1) part += __shfl_xor(part,off);
  __shared__ float rs[4];
  if ((tid&63)==0) rs[tid>>6]=part;
  __syncthreads();
  if (tid==0) b1p[o] = b1[o] + rs[0]+rs[1]+rs[2]+rs[3];
}

// ---------------- conv1 MFMA: feature gen (fast exp) -> bf16 LDS; out Z1 bf16 + bn1 partials ----
__launch_bounds__(256)
__global__ void k_conv1mf(const float* __restrict__ L, const float* __restrict__ PL,
                          const float* __restrict__ PI, const float* __restrict__ DSF,
                          const unsigned short* __restrict__ W1B, const float* __restrict__ b1p,
                          unsigned short* __restrict__ Z1B, float* __restrict__ ps){
  __shared__ __align__(16) unsigned short Abuf[64*K1P];
  __shared__ __align__(16) unsigned short Bbuf[64*K1P];
  __shared__ float pl_s[64], pi_s[64];
  __shared__ float red[4][2][64];
  int tid = threadIdx.x;
  int r0 = blockIdx.x*64;
  if (tid < 64){
    int r = r0+tid; int m = r/500; int n = r - m*500; int b = m >> 5;
    pl_s[tid] = PL[b*Nn+n]; pi_s[tid] = PI[b*Nn+n];
  }
  for (int e=tid; e<64*28; e+=256){
    int row = e/28; int kc = (e - row*28)*8;
    short8 w = *(const short8*)&W1B[row*K1P + kc];
    unsigned byte = ((unsigned)(row*K1P + kc))*2u ^ (((unsigned)(row&7))<<4);
    *(short8*)((char*)Bbuf + byte) = w;
  }
  __syncthreads();
  float cfac = sigf(DSF[0])*200000.0f;
  for (int e=tid; e<64*28; e+=256){
    int row = e/28; int j0 = (e - row*28)*8;
    int am = (r0+row)/500;
    float pl = pl_s[row];
    float v[8];
    if (j0 < 208){
      float4 la = *(const float4*)&L[(size_t)am*208 + j0];
      float4 lb = *(const float4*)&L[(size_t)am*208 + j0 + 4];
      float li[8] = {la.x,la.y,la.z,la.w,lb.x,lb.y,lb.z,lb.w};
      #pragma unroll
      for (int j=0;j<8;j++)
        v[j] = (li[j] > 1e-5f && pl > 1e-5f)
             ? __expf(-fabsf((pl-li[j])*frcp(li[j]+1e-6f))*cfac) : 0.f;
    } else {
      #pragma unroll
      for (int j=0;j<8;j++) v[j] = 0.f;
      if (j0 == 208) v[0] = pi_s[row];
    }
    short8 st;
    #pragma unroll
    for (int j=0;j<8;j++) st[j] = (short)f2bf(v[j]);
    unsigned byte = ((unsigned)(row*K1P + j0))*2u ^ (((unsigned)(row&7))<<4);
    *(short8*)((char*)Abuf + byte) = st;
  }
  __syncthreads();
  int lane = tid&63, wid = tid>>6;
  int l15 = lane&15, lhi = lane>>4;
  int ar = wid*16 + l15;
  unsigned aswz = ((unsigned)(ar&7))<<4;
  f32x4 acc[4] = {};
  #pragma unroll
  for (int ks=0; ks<7; ks++){
    int kb = ks*32 + lhi*8;
    short8 af = *(const short8*)((const char*)Abuf + ((((unsigned)(ar*K1P + kb))*2u) ^ aswz));
    #pragma unroll
    for (int fj=0; fj<4; fj++){
      int bc = fj*16 + l15;
      short8 bfv = *(const short8*)((const char*)Bbuf + ((((unsigned)(bc*K1P + kb))*2u) ^ (((unsigned)(bc&7))<<4)));
      acc[fj] = __builtin_amdgcn_mfma_f32_16x16x32_bf16(af, bfv, acc[fj], 0, 0, 0);
    }
  }
  #pragma unroll
  for (int fj=0; fj<4; fj++){
    int ch = fj*16 + l15;
    float bc = b1p[ch];
    float s=0.f, q=0.f;
    #pragma unroll
    for (int qi=0; qi<4; qi++){
      float zv = acc[fj][qi] + bc;
      int rg = r0 + wid*16 + lhi*4 + qi;
      Z1B[(size_t)rg*Uu + ch] = f2bf(zv);
      s += zv; q += zv*zv;
    }
    s += __shfl_xor(s,16); s += __shfl_xor(s,32);
    q += __shfl_xor(q,16); q += __shfl_xor(q,32);
    if (lhi == 0){ red[wid][0][ch]=s; red[wid][1][ch]=q; }
  }
  __syncthreads();
  if (tid < 64){
    float s = red[0][0][tid]+red[1][0][tid]+red[2][0][tid]+red[3][0][tid];
    float q = red[0][1][tid]+red[1][1][tid]+red[2][1][tid]+red[3][1][tid];
    ps[(size_t)blockIdx.x*Uu + tid] = s;
    ps[(size_t)(NB1 + blockIdx.x)*Uu + tid] = q;
  }
}

// ---------------- conv2 MFMA: A = relu(bn1(Z1B)) bf16, 128x128 tile, K=64 ----------------
__launch_bounds__(256)
__global__ void k_convmf(const unsigned short* __restrict__ Xin, const float* __restrict__ abbIn,
                         const unsigned short* __restrict__ Wb, int Ctot,
                         const float* __restrict__ bias, unsigned short* __restrict__ Zout,
                         float* __restrict__ ps, int NB){
  constexpr int K = 64;
  __shared__ __align__(16) unsigned short Abuf[128*K];
  __shared__ __align__(16) unsigned short Bbuf[128*K];
  __shared__ float abbs[2*K];
  __shared__ float redS[2][128], redQ[2][128];
  int tid = threadIdx.x;
  int r0 = blockIdx.x*128;
  int c0 = 0;
  for (int e=tid; e<2*K; e+=256) abbs[e] = abbIn[e];
  __syncthreads();
  constexpr int CPR = K/8;
  for (int e=tid; e<128*CPR; e+=256){
    int row = e/CPR; int kc = (e - row*CPR)*8;
    short8 rawv = *(const short8*)(Xin + (size_t)(r0+row)*K + kc);
    short8 st;
    #pragma unroll
    for (int j=0;j<8;j++){
      float t = fmaxf(abbs[kc+j]*bf2f((unsigned short)rawv[j]) + abbs[K+kc+j], 0.f);
      st[j] = (short)f2bf(t);
    }
    unsigned byte = ((unsigned)(row*K + kc))*2u; byte ^= ((unsigned)(row&7))<<4;
    *(short8*)((char*)Abuf + byte) = st;
  }
  for (int e=tid; e<128*CPR; e+=256){
    int row = e/CPR; int kc = (e - row*CPR)*8;
    short8 w = *(const short8*)&Wb[(size_t)(c0+row)*K + kc];
    unsigned byte = ((unsigned)(row*K + kc))*2u; byte ^= ((unsigned)(row&7))<<4;
    *(short8*)((char*)Bbuf + byte) = w;
  }
  __syncthreads();

  int lane = tid&63, wid = tid>>6;
  int wr = wid>>1, wc = wid&1;
  int l15 = lane&15, lhi = lane>>4;
  f32x4 acc[4][4] = {};
  #pragma unroll
  for (int ks=0; ks<K/32; ks++){
    short8 af[4], bfr[4];
    int kb = ks*32 + lhi*8;
    #pragma unroll
    for (int f=0; f<4; f++){
      int arr = wr*64 + f*16 + l15;
      unsigned ab = ((unsigned)(arr*K + kb))*2u ^ (((unsigned)(arr&7))<<4);
      af[f] = *(const short8*)((const char*)Abuf + ab);
      int bc = wc*64 + f*16 + l15;
      unsigned bb = ((unsigned)(bc*K + kb))*2u ^ (((unsigned)(bc&7))<<4);
      bfr[f] = *(const short8*)((const char*)Bbuf + bb);
    }
    #pragma unroll
    for (int fi=0; fi<4; fi++)
      #pragma unroll
      for (int fj=0; fj<4; fj++)
        acc[fi][fj] = __builtin_amdgcn_mfma_f32_16x16x32_bf16(af[fi], bfr[fj], acc[fi][fj], 0, 0, 0);
  }

  #pragma unroll
  for (int fj=0; fj<4; fj++){
    int cg = c0 + wc*64 + fj*16 + l15;
    float bc = bias[cg];
    float s=0.f, q=0.f;
    #pragma unroll
    for (int fi=0; fi<4; fi++){
      #pragma unroll
      for (int qi=0; qi<4; qi++){
        float zv = acc[fi][fj][qi] + bc;
        int rg = r0 + wr*64 + fi*16 + lhi*4 + qi;
        Zout[(size_t)rg*Ctot + cg] = f2bf(zv);
        s += zv; q += zv*zv;
      }
    }
    s += __shfl_xor(s,16); s += __shfl_xor(s,32);
    q += __shfl_xor(q,16); q += __shfl_xor(q,32);
    if (lhi == 0){
      int ch = wc*64 + fj*16 + l15;
      redS[wr][ch]=s; redQ[wr][ch]=q;
    }
  }
  __syncthreads();
  if (tid < 128){
    float s = redS[0][tid]+redS[1][tid];
    float q = redQ[0][tid]+redQ[1][tid];
    size_t ci = (size_t)blockIdx.x*Ctot + c0 + tid;
    ps[ci] = s;
    ps[(size_t)NB*Ctot + ci] = q;
  }
}

// ---------------- conv3 MFMA: c-loop over two 128-col halves; A staged once ----------------
__launch_bounds__(256)
__global__ void k_conv3mf(const unsigned short* __restrict__ Xin, const float* __restrict__ abbIn,
                          const unsigned short* __restrict__ Wb,
                          const float* __restrict__ bias,
                          float* __restrict__ ps, int NB,
                          float* __restrict__ pm, float* __restrict__ pn){
  constexpr int K = 128, Ctot = 256;
  __shared__ __align__(16) unsigned short Abuf[128*K];
  __shared__ __align__(16) unsigned short Bbuf[128*K];
  __shared__ float abbs[2*K];
  __shared__ float redS[2][128], redQ[2][128];
  __shared__ float mxS[2][2][128], mnS[2][2][128];
  int tid = threadIdx.x;
  int r0 = blockIdx.x*128;
  for (int e=tid; e<2*K; e+=256) abbs[e] = abbIn[e];
  __syncthreads();
  constexpr int CPR = K/8;
  for (int e=tid; e<128*CPR; e+=256){
    int row = e/CPR; int kc = (e - row*CPR)*8;
    short8 rawv = *(const short8*)(Xin + (size_t)(r0+row)*K + kc);
    short8 st;
    #pragma unroll
    for (int j=0;j<8;j++){
      float t = fmaxf(abbs[kc+j]*bf2f((unsigned short)rawv[j]) + abbs[K+kc+j], 0.f);
      st[j] = (short)f2bf(t);
    }
    unsigned byte = ((unsigned)(row*K + kc))*2u; byte ^= ((unsigned)(row&7))<<4;
    *(short8*)((char*)Abuf + byte) = st;
  }

  int lane = tid&63, wid = tid>>6;
  int wr = wid>>1, wc = wid&1;
  int l15 = lane&15, lhi = lane>>4;
  int m0 = r0/500;
  int mhi = (m0+1)*500;

  for (int half=0; half<2; half++){
    int c0 = half*128;
    __syncthreads();   // prior Bbuf/red reads done (and A-stage on half 0)
    for (int e=tid; e<128*CPR; e+=256){
      int row = e/CPR; int kc = (e - row*CPR)*8;
      short8 w = *(const short8*)&Wb[(size_t)(c0+row)*K + kc];
      unsigned byte = ((unsigned)(row*K + kc))*2u; byte ^= ((unsigned)(row&7))<<4;
      *(short8*)((char*)Bbuf + byte) = w;
    }
    __syncthreads();

    f32x4 acc[4][4] = {};
    #pragma unroll
    for (int ks=0; ks<K/32; ks++){
      short8 af[4], bfr[4];
      int kb = ks*32 + lhi*8;
      #pragma unroll
      for (int f=0; f<4; f++){
        int arr = wr*64 + f*16 + l15;
        unsigned ab = ((unsigned)(arr*K + kb))*2u ^ (((unsigned)(arr&7))<<4);
        af[f] = *(const short8*)((const char*)Abuf + ab);
        int bc = wc*64 + f*16 + l15;
        unsigned bb = ((unsigned)(bc*K + kb))*2u ^ (((unsigned)(bc&7))<<4);
        bfr[f] = *(const short8*)((const char*)Bbuf + bb);
      }
      #pragma unroll
      for (int fi=0; fi<4; fi++)
        #pragma unroll
        for (int fj=0; fj<4; fj++)
          acc[fi][fj] = __builtin_amdgcn_mfma_f32_16x16x32_bf16(af[fi], bfr[fj], acc[fi][fj], 0, 0, 0);
    }

    #pragma unroll
    for (int fj=0; fj<4; fj++){
      int cg = c0 + wc*64 + fj*16 + l15;
      float bc = bias[cg];
      float s=0.f, q=0.f;
      float mx0=-INFINITY,mx1=-INFINITY,mn0=INFINITY,mn1=INFINITY;
      #pragma unroll
      for (int fi=0; fi<4; fi++){
        #pragma unroll
        for (int qi=0; qi<4; qi++){
          float zv = acc[fi][fj][qi] + bc;
          int rg = r0 + wr*64 + fi*16 + lhi*4 + qi;
          s += zv; q += zv*zv;
          if (rg >= mhi){ mx1=fmaxf(mx1,zv); mn1=fminf(mn1,zv); }
          else          { mx0=fmaxf(mx0,zv); mn0=fminf(mn0,zv); }
        }
      }
      s += __shfl_xor(s,16); s += __shfl_xor(s,32);
      q += __shfl_xor(q,16); q += __shfl_xor(q,32);
      mx0 = fmaxf(mx0, __shfl_xor(mx0,16)); mx0 = fmaxf(mx0, __shfl_xor(mx0,32));
      mx1 = fmaxf(mx1, __shfl_xor(mx1,16)); mx1 = fmaxf(mx1, __shfl_xor(mx1,32));
      mn0 = fminf(mn0, __shfl_xor(mn0,16)); mn0 = fminf(mn0, __shfl_xor(mn0,32));
      mn1 = fminf(mn1, __shfl_xor(mn1,16)); mn1 = fminf(mn1, __shfl_xor(mn1,32));
      if (lhi == 0){
        int ch = wc*64 + fj*16 + l15;
        redS[wr][ch]=s; redQ[wr][ch]=q;
        mxS[wr][0][ch]=mx0; mxS[wr][1][ch]=mx1;
        mnS[wr][0][ch]=mn0; mnS[wr][1][ch]=mn1;
      }
    }
    __syncthreads();
    if (tid < 128){
      float s = redS[0][tid]+redS[1][tid];
      float q = redQ[0][tid]+redQ[1][tid];
      size_t ci = (size_t)blockIdx.x*Ctot + c0 + tid;
      ps[ci] = s;
      ps[(size_t)NB*Ctot + ci] = q;
      #pragma unroll
      for (int g=0; g<2; g++){
        pm[((size_t)blockIdx.x*2+g)*Ctot + c0 + tid] = fmaxf(mxS[0][g][tid], mxS[1][g][tid]);
        pn[((size_t)blockIdx.x*2+g)*Ctot + c0 + tid] = fminf(mnS[0][g][tid], mnS[1][g][tid]);
      }
    }
  }
}

// per-(m,c) max/min over contributing row-blocks, fused with pool epilogue
__global__ void k_poolmm(const float* __restrict__ pm, const float* __restrict__ pn,
                         const float* __restrict__ abb3, float* __restrict__ P){
  int idx = blockIdx.x*blockDim.x + threadIdx.x;
  if (idx >= Mm*256) return;
  int m = idx>>8, c = idx&255;
  int bxlo = (500*m)/128;
  int bxhi = (500*m+499)/128;
  float mx=-INFINITY, mn=INFINITY;
  for (int bx=bxlo; bx<=bxhi; bx++){
    int m0 = (bx*128)/500;
    int gg = m - m0;
    if (gg==0 || gg==1){
      mx = fmaxf(mx, pm[((size_t)bx*2+gg)*256 + c]);
      mn = fminf(mn, pn[((size_t)bx*2+gg)*256 + c]);
    }
  }
  float a = abb3[c], bb = abb3[256+c];
  float zv = (a >= 0.f) ? mx : mn;
  P[idx] = fmaxf(a*zv + bb, 0.f);
}

// ---------------- generic tiled GEMM: C = opt_relu_bn(A) @ Wt + bias1 (+bias2) ----------------
__launch_bounds__(256)
__global__ void k_gemm(const float* __restrict__ A, const float* __restrict__ Wt,
                       const float* __restrict__ bias1, const float* __restrict__ bias2,
                       const float* __restrict__ abb,
                       float* __restrict__ Cmat, int Mrows, int Nc, int K){
  __shared__ float As[64][66];
  __shared__ float Bs[64][64];
  int tid = threadIdx.x;
  int r0 = blockIdx.x*64, c0 = blockIdx.y*64;
  int ty=tid>>4, tx=tid&15;
  float acc[4][4]={};
  for (int kc=0; kc<K; kc+=64){
    for (int e=tid; e<4096; e+=256){
      int i=e>>6, k=e&63;
      int r = r0+i;
      float v = (r < Mrows) ? A[(size_t)r*K + kc + k] : 0.f;
      if (abb) v = fmaxf(abb[kc+k]*v + abb[K+kc+k], 0.f);
      As[i][k]=v;
    }
    for (int e=tid; e<4096; e+=256){
      int k=e>>6, c=e&63;
      Bs[k][c] = Wt[(size_t)(kc+k)*Nc + c0 + c];
    }
    __syncthreads();
    #pragma unroll 4
    for (int k=0;k<64;k++){
      float a0=As[ty*4+0][k],a1=As[ty*4+1][k],a2=As[ty*4+2][k],a3=As[ty*4+3][k];
      float4 bv = *(const float4*)&Bs[k][tx*4];
      mac44r(acc,a0,a1,a2,a3,bv);
    }
    __syncthreads();
  }
  #pragma unroll
  for (int i=0;i<4;i++){
    int r = r0+ty*4+i; if (r >= Mrows) continue;
    #pragma unroll
    for (int j=0;j<4;j++){
      int c = c0+tx*4+j;
      float zv = acc[i][j] + bias1[c] + (bias2 ? bias2[c] : 0.f);
      Cmat[(size_t)r*Nc + c] = zv;
    }
  }
}

// one LSTM step; 256 blocks x 128 thr; block handles 2 u-columns x 4 gates x 16 batch
__launch_bounds__(128)
__global__ void k_lstm_step(const float* __restrict__ hprev, float* __restrict__ hnext,
                            const float* __restrict__ cin, float* __restrict__ cout,
                            const float* __restrict__ embw, const int* __restrict__ aa,
                            const float* __restrict__ whh, float* __restrict__ lout,
                            float* __restrict__ outhc, int t){
  __shared__ float h_s[16][516];
  __shared__ float g_s[16][8];
  int tid = threadIdx.x;
  int u0 = blockIdx.x*2;
  for (int e=tid; e<2048; e+=128){
    int idx = e*4;
    *(float4*)&h_s[idx>>9][idx&511] = *(const float4*)&hprev[idx];
  }
  __syncthreads();
  int b = tid>>3, gu = tid&7, gate = gu>>1, uu = gu&1;
  int j = gate*512 + u0 + uu;
  const float4* wrow = (const float4*)&whh[(size_t)j*512];
  const float4* hrow = (const float4*)&h_s[b][0];
  float acc = 0.f;
  #pragma unroll 4
  for (int k=0;k<128;k++){
    float4 wv = wrow[k]; float4 hv = hrow[k];
    acc = fmaf(hv.x,wv.x,acc); acc = fmaf(hv.y,wv.y,acc);
    acc = fmaf(hv.z,wv.z,acc); acc = fmaf(hv.w,wv.w,acc);
  }
  int v = aa[b*Tt + t];
  acc += embw[(size_t)v*2048 + j];
  g_s[b][gu] = acc;
  __syncthreads();
  if (tid < 32){
    int bb = tid>>1, up = tid&1;
    float iv = g_s[bb][0+up], fv = g_s[bb][2+up], gv = g_s[bb][4+up], ov = g_s[bb][6+up];
    int ci = bb*512 + u0 + up;
    float cn = sigf(fv)*cin[ci] + sigf(iv)*tanhf(gv);
    float hn = sigf(ov)*tanhf(cn);
    cout[ci]=cn; hnext[ci]=hn;
    lout[(size_t)(bb*Tt + t)*Hh + u0 + up] = hn;
    if (outhc){ outhc[Mm*Vv + ci] = hn; outhc[Mm*Vv + Bb*Hh + ci] = cn; }
  }
}

__global__ void k_logits(const float* __restrict__ Z5, const float* __restrict__ abb5,
                         const float* __restrict__ lout, const float* __restrict__ outw,
                         const float* __restrict__ outb, float* __restrict__ out){
  int idx = blockIdx.x*blockDim.x + threadIdx.x;
  if (idx >= Mm*Vv) return;
  int r = idx / Vv, o = idx - r*Vv;
  float acc = outb[o];
  for (int k=0;k<64;k++){
    float v = fmaxf(abb5[k]*Z5[(size_t)r*64+k] + abb5[64+k], 0.f);
    acc = fmaf(v, outw[o*576 + k], acc);
  }
  for (int k=0;k<512;k++){
    float v = fmaxf(lout[(size_t)r*512 + k], 0.f);
    acc = fmaf(v, outw[o*576 + 64 + k], acc);
  }
  out[idx] = acc;
}

extern "C" void kernel_launch(void* const* d_in, const int* in_sizes, int n_in,
                              void* d_out, int out_size, void* d_ws, size_t ws_size,
                              hipStream_t stream){
  (void)in_sizes; (void)n_in; (void)out_size; (void)ws_size;
  const float* L   = (const float*)d_in[0];
  const float* PL  = (const float*)d_in[1];
  const float* PI  = (const float*)d_in[2];
  const int*   AA  = (const int*)d_in[3];
  const float* H0  = (const float*)d_in[4];
  const float* C0  = (const float*)d_in[5];
  const float* DSF = (const float*)d_in[6];
  const float* W1  = (const float*)d_in[7];
  const float* B1  = (const float*)d_in[8];
  const float* W2  = (const float*)d_in[9];
  const float* B2  = (const float*)d_in[10];
  const float* W3  = (const float*)d_in[11];
  const float* B3  = (const float*)d_in[12];
  const float* FC1W= (const float*)d_in[13];
  const float* FC1B= (const float*)d_in[14];
  const float* FC2W= (const float*)d_in[15];
  const float* FC2B= (const float*)d_in[16];
  const float* G0=(const float*)d_in[17]; const float* Bt0=(const float*)d_in[18];
  const float* G1=(const float*)d_in[19]; const float* Bt1=(const float*)d_in[20];
  const float* G2=(const float*)d_in[21]; const float* Bt2=(const float*)d_in[22];
  const float* G3=(const float*)d_in[23]; const float* Bt3=(const float*)d_in[24];
  const float* G4=(const float*)d_in[25]; const float* Bt4=(const float*)d_in[26];
  const float* G5=(const float*)d_in[27]; const float* Bt5=(const float*)d_in[28];
  const float* EMB=(const float*)d_in[29];
  const float* WIH=(const float*)d_in[30];
  const float* WHH=(const float*)d_in[31];
  const float* BIH=(const float*)d_in[32];
  const float* BHH=(const float*)d_in[33];
  const float* OUTW=(const float*)d_in[34];
  const float* OUTB=(const float*)d_in[35];
  float* out = (float*)d_out;
  float* ws  = (float*)d_ws;

  size_t o = 0;
  unsigned short* Z1B = (unsigned short*)(ws+o); o += (size_t)Rr*32;   // Rr*64 bf16
  unsigned short* Z2B = (unsigned short*)(ws+o); o += (size_t)Rr*64;   // Rr*128 bf16
  float* PS0   = ws+o; o += 2*512*CIN + 16;
  float* PS1   = ws+o; o += 2*NB1*64 + 16;
  float* PS2   = ws+o; o += 2*NB23*128 + 16;
  float* PS3   = ws+o; o += 2*NB23*256 + 16;
  float* PM3   = ws+o; o += NB23*2*256 + 16;
  float* PN3   = ws+o; o += NB23*2*256 + 16;
  float* ABB0  = ws+o; o += 432;
  float* ABB1  = ws+o; o += 128;
  float* ABB2  = ws+o; o += 256;
  float* ABB3  = ws+o; o += 512;
  float* ABB4  = ws+o; o += 256;
  float* ABB5  = ws+o; o += 128;
  unsigned short* W1B = (unsigned short*)(ws+o); o += 64*K1P/2 + 16;
  float* B1P   = ws+o; o += 64;
  unsigned short* W2B = (unsigned short*)(ws+o); o += 4096 + 16;
  unsigned short* W3B = (unsigned short*)(ws+o); o += 16384 + 16;
  float* Pm    = ws+o; o += 131072;
  float* Z4    = ws+o; o += 65536;
  float* Z5    = ws+o; o += 32768;
  float* EMBW  = ws+o; o += 53248;
  float* WIHT  = ws+o; o += 1048576;
  float* FC1T  = ws+o; o += 32768;
  float* FC2T  = ws+o; o += 8192;
  float* HB0   = ws+o; o += 8192;
  float* HB1   = ws+o; o += 8192;
  float* CB    = ws+o; o += 8192;
  float* LOUT  = ws+o; o += 262144;

  // weight prep (independent of data)
  k_transT<<<dim3(8,32),256,0,stream>>>(WIH, WIHT, 2048, 512);
  k_prep<<<320,256,0,stream>>>(W2,W3,FC1W,FC2W,W2B,W3B,FC1T,FC2T);

  // point cloud branch
  k_feat_stats<<<512,256,0,stream>>>(L,PL,PI,DSF,PS0);
  k_reduce_ps<<<CIN,256,0,stream>>>(PS0, 512, CIN, 1.0f/(float)Rr, G0, Bt0, ABB0);
  k_fold_w1p<<<64,256,0,stream>>>(W1,B1,ABB0,W1B,B1P);
  k_conv1mf<<<NB1,256,0,stream>>>(L,PL,PI,DSF,W1B,B1P,Z1B,PS1);
  k_reduce_ps<<<64,256,0,stream>>>(PS1, NB1, 64, 1.0f/(float)Rr, G1, Bt1, ABB1);
  k_convmf<<<NB23,256,0,stream>>>(Z1B,ABB1,W2B,128,B2,Z2B,PS2,NB23);
  k_reduce_ps<<<128,256,0,stream>>>(PS2, NB23, 128, 1.0f/(float)Rr, G2, Bt2, ABB2);
  k_conv3mf<<<NB23,256,0,stream>>>(Z2B,ABB2,W3B,B3,PS3,NB23,PM3,PN3);
  k_reduce_ps<<<256,256,0,stream>>>(PS3, NB23, 256, 1.0f/(float)Rr, G3, Bt3, ABB3);
  k_poolmm<<<512,256,0,stream>>>(PM3,PN3,ABB3,Pm);
  k_gemm<<<dim3(8,2),256,0,stream>>>(Pm,FC1T,FC1B,nullptr,nullptr,Z4,512,128,256);
  k_colstats_par<<<128,256,0,stream>>>(Z4,512,128,G4,Bt4,ABB4);
  k_gemm<<<dim3(8,1),256,0,stream>>>(Z4,FC2T,FC2B,nullptr,ABB4,Z5,512,64,128);
  k_colstats_par<<<64,256,0,stream>>>(Z5,512,64,G5,Bt5,ABB5);

  // LSTM branch — embw precompute then 32 step launches (init/out fused into steps 0/31)
  k_gemm<<<dim3(1,32),256,0,stream>>>(EMB,WIHT,BIH,BHH,nullptr,EMBW,26,2048,512);
  for (int t=0;t<32;t++){
    const float* hp = (t==0) ? H0 : ((t&1)?HB1:HB0);
    float* hn = (t&1)?HB0:HB1;
    const float* ci = (t==0) ? C0 : CB;
    float* outhc = (t==31) ? out : nullptr;
    k_lstm_step<<<256,128,0,stream>>>(hp,hn,ci,CB,EMBW,AA,WHH,LOUT,outhc,t);
  }

  // output head
  k_logits<<<52,256,0,stream>>>(Z5,ABB5,LOUT,OUTW,OUTB,out);
}